// Round 3
// baseline (122.357 us; speedup 1.0000x reference)
//
#include <hip/hip_runtime.h>
#include <math.h>

#define BB 8
#define NN 1024
#define MM 128
#define FOUT 64
#define HIDN 128

// ---------------- workspace layout (floats) ----------------
#define OFF_H       0                       // B*N*64 = 524288
#define OFF_HMA     524288                  // B*M*64 = 65536
#define OFF_HA1     589824                  // B*N
#define OFF_HA2     598016                  // B*N
#define OFF_HAM1    606208                  // B*N
#define OFF_HMAAM2  614400                  // B*M
#define OFF_RMASK   615424                  // B*N (ints)
#define OFF_WAM3    623616                  // 16
#define OFF_HPRIME  623632                  // B*N*128 = 1048576
#define OFF_UPACK   1672208                 // B*N*32 u32 = 262144 words
#define OFF_OPMB    1934352                 // B*N*2 u64 = 32768 floats
// total ~1,967,120 floats ~ 7.9 MB

// ================= Kernel 1 (fused): h, h_ma, dots, rmask, opma bits, wam3,
//                   and adjacency bit-pack u = (op|op^T|ma|ma^T)>0 ===========
__global__ __launch_bounds__(256) void k1_prep(
    const float* __restrict__ x, const float* __restrict__ y,
    const int* __restrict__ op_ma_adj,
    const int* __restrict__ op_adj, const int* __restrict__ ma_adj,
    const float* __restrict__ w_op, const float* __restrict__ w_ma,
    const float* __restrict__ w_edge,
    const float* __restrict__ att_op, const float* __restrict__ att_ma,
    float* __restrict__ h, float* __restrict__ h_ma,
    float* __restrict__ ha1, float* __restrict__ ha2, float* __restrict__ ham1,
    float* __restrict__ hmaam2, int* __restrict__ rmask, float* __restrict__ wam3,
    unsigned* __restrict__ upack, unsigned long long* __restrict__ opmb)
{
    __shared__ float wlds[64 * 64];
    int bid = blockIdx.x;
    int t = threadIdx.x;
    int lane = t & 63;
    int wv = t >> 6;

    if (bid < 2048) {
        for (int k = t; k < 4096; k += 256) wlds[k] = w_op[k];
        __syncthreads();
        int row = bid * 4 + wv;                 // b*N + n, 0..8191
        float xv = x[(size_t)row * 64 + lane];
        float acc = 0.f;
        #pragma unroll
        for (int i = 0; i < 64; ++i) {
            float xi = __shfl(xv, i);
            acc += xi * wlds[i * 64 + lane];
        }
        h[(size_t)row * 64 + lane] = acc;
        float d1 = acc * att_op[lane];          // a1
        float d2 = acc * att_op[64 + lane];     // a2
        float d3 = acc * att_ma[lane];          // am1
        #pragma unroll
        for (int m = 32; m; m >>= 1) {
            d1 += __shfl_xor(d1, m);
            d2 += __shfl_xor(d2, m);
            d3 += __shfl_xor(d3, m);
        }
        int v0 = op_ma_adj[(size_t)row * 128 + lane];
        int v1 = op_ma_adj[(size_t)row * 128 + 64 + lane];
        unsigned long long w0 = __ballot(v0 != 0);
        unsigned long long w1 = __ballot(v1 != 0);
        if (lane == 0) {
            ha1[row] = d1; ha2[row] = d2; ham1[row] = d3;
            opmb[row * 2] = w0; opmb[row * 2 + 1] = w1;
            rmask[row] = ((w0 | w1) == 0ULL) ? 1 : 0;
        }
    } else if (bid < 2048 + 256) {
        for (int k = t; k < 4096; k += 256) wlds[k] = w_ma[k];
        __syncthreads();
        int row = (bid - 2048) * 4 + wv;        // b*M + m, 0..1023
        float yv = y[(size_t)row * 64 + lane];
        float acc = 0.f;
        #pragma unroll
        for (int i = 0; i < 64; ++i) {
            float yi = __shfl(yv, i);
            acc += yi * wlds[i * 64 + lane];
        }
        h_ma[(size_t)row * 64 + lane] = acc;
        float d = acc * att_ma[64 + lane];      // am2
        #pragma unroll
        for (int m = 32; m; m >>= 1) d += __shfl_xor(d, m);
        if (lane == 0) hmaam2[row] = d;
    } else if (bid == 2304) {
        if (t < 16) {
            float s = 0.f;
            for (int o = 0; o < 64; ++o) s += w_edge[t * 64 + o] * att_ma[128 + o];
            wam3[t] = s;
        }
    } else {
        // ---- adjacency bit-pack: tile pair (I,J), I<=J, per batch ----
        unsigned* sAB = (unsigned*)wlds;        // [2][64][2]
        int p = bid - 2305;                     // 0..1087
        int b = p / 136;
        int pr = p % 136;
        int I = 0;
        { int rem = pr, cnt = 16;
          while (rem >= cnt) { rem -= cnt; cnt--; I++; }
          pr = rem; }
        int J = I + pr;

        int c = t & 63, hr = (t >> 6) & 1, ts = t >> 7;
        int Ia = ts ? J : I, Ja = ts ? I : J;
        const int* opb = op_adj + (size_t)b * NN * NN + (size_t)(Ia * 64) * NN + Ja * 64;
        const int* mab = ma_adj + (size_t)b * NN * NN + (size_t)(Ia * 64) * NN + Ja * 64;
        unsigned w = 0;
        #pragma unroll 8
        for (int k = 0; k < 32; ++k) {
            int r = hr * 32 + k;
            int aval = opb[(size_t)r * NN + c] | mab[(size_t)r * NN + c];
            w |= (aval ? 1u : 0u) << k;
        }
        sAB[ts * 128 + c * 2 + hr] = w;
        __syncthreads();
        if (t < 128) {
            int r = t & 63, hh = t >> 6;
            int rw = r >> 5, rb = r & 31;
            unsigned dir1 = sAB[128 + r * 2 + hh];   // t2[c][r] bits
            unsigned dir2 = sAB[r * 2 + hh];         // t1[c][r] bits
            unsigned wt1 = 0, wt2 = 0;
            #pragma unroll 8
            for (int k = 0; k < 32; ++k) {
                int cc = hh * 32 + k;
                wt1 |= ((sAB[cc * 2 + rw] >> rb) & 1u) << k;        // t1[r][cc]
                wt2 |= ((sAB[128 + cc * 2 + rw] >> rb) & 1u) << k;  // t2[r][cc]
            }
            upack[((size_t)(b * NN + I * 64 + r)) * 32 + J * 2 + hh] = dir1 | wt1;
            upack[((size_t)(b * NN + J * 64 + r)) * 32 + I * 2 + hh] = dir2 | wt2;
        }
    }
}

// ================= Kernel 2: op attention + h_prime_op ======================
// block = 256 threads, one block per (b, 8-row tile).
__global__ __launch_bounds__(256) void k2_opatt(
    const unsigned* __restrict__ upack,
    const float* __restrict__ h, const float* __restrict__ ha1,
    const float* __restrict__ ha2, const int* __restrict__ rmask,
    float* __restrict__ h_prime)
{
    __shared__ float smem[8 * 1032];
    __shared__ float ha1s[1024];
    __shared__ unsigned uw[8 * 32];
    __shared__ float denom[8];
    int bid = blockIdx.x;
    int b = bid >> 7;
    int i0 = (bid & 127) * 8;
    int t = threadIdx.x;

    uw[t & 255] = upack[((size_t)(b * NN + i0)) * 32 + t];
    for (int k = t; k < 1024; k += 256) ha1s[k] = ha1[b * NN + k];
    __syncthreads();

    // phase 1: masked e, per-row max/sumexp, store unnormalized exp in LDS
    int ii = t >> 5, l = t & 31;
    int i = i0 + ii;
    float ha2i = ha2[b * NN + i];
    unsigned rm = rmask[b * NN + i] ? 0xFFFFFFFFu : 0u;
    float e[32];
    #pragma unroll
    for (int it = 0; it < 32; ++it) {
        int j = l + 32 * it;
        unsigned w = uw[ii * 32 + it] | rm;
        float ev = ha2i + ha1s[j];
        ev = ev > 0.f ? ev : 0.01f * ev;
        e[it] = ((w >> l) & 1u) ? ev : -INFINITY;
    }
    float mx = -INFINITY;
    #pragma unroll
    for (int it = 0; it < 32; ++it) mx = fmaxf(mx, e[it]);
    #pragma unroll
    for (int msk = 16; msk; msk >>= 1) mx = fmaxf(mx, __shfl_xor(mx, msk));
    float s = 0.f;
    #pragma unroll
    for (int it = 0; it < 32; ++it) {
        float u = __expf(e[it] - mx);
        smem[ii * 1032 + l + 32 * it] = u;
        s += u;
    }
    #pragma unroll
    for (int msk = 16; msk; msk >>= 1) s += __shfl_xor(s, msk);
    if (l == 0) denom[ii] = s;
    __syncthreads();

    // phase 2: h_prime_op[k][o] = sum_j u[k][j] * h[b][j][o]
    {
        int wv = t >> 6, o = t & 63;
        float acc[8];
        #pragma unroll
        for (int k = 0; k < 8; ++k) acc[k] = 0.f;
        const float* hb = h + (size_t)b * NN * 64;
        for (int jg = wv * 64; jg < wv * 64 + 64; ++jg) {
            int j = jg * 4;
            float h0 = hb[(size_t)(j + 0) * 64 + o];
            float h1 = hb[(size_t)(j + 1) * 64 + o];
            float h2 = hb[(size_t)(j + 2) * 64 + o];
            float h3 = hb[(size_t)(j + 3) * 64 + o];
            #pragma unroll
            for (int k = 0; k < 8; ++k) {
                float4 u4 = *(const float4*)&smem[k * 1032 + j];
                acc[k] += u4.x * h0 + u4.y * h1 + u4.z * h2 + u4.w * h3;
            }
        }
        __syncthreads();            // everyone done reading u
        #pragma unroll
        for (int k = 0; k < 8; ++k) smem[(wv * 8 + k) * 64 + o] = acc[k];
        __syncthreads();
        int oo = t & 63;
        int k0 = t >> 6;            // handles rows k0 and k0+4
        for (int kk = k0; kk < 8; kk += 4) {
            float v = smem[kk * 64 + oo] + smem[(8 + kk) * 64 + oo]
                    + smem[(16 + kk) * 64 + oo] + smem[(24 + kk) * 64 + oo];
            v /= denom[kk];
            h_prime[((size_t)(b * NN + i0 + kk)) * 128 + oo] = v;
        }
    }
}

// ================= Kernel 3: ma attention + h_prime_ma ======================
// block = 256 threads, handles 8 n's (2 at a time); h_ma staged in LDS.
__global__ __launch_bounds__(256) void k3_maatt(
    const float* __restrict__ z, const unsigned long long* __restrict__ opmb,
    const float* __restrict__ h, const float* __restrict__ h_ma,
    const float* __restrict__ ham1, const float* __restrict__ hmaam2,
    const int* __restrict__ rmask, const float* __restrict__ wam3,
    const float* __restrict__ w_edge, float* __restrict__ h_prime)
{
    __shared__ float hma_s[128 * 64];      // 32 KB
    __shared__ float u_s[2][128];
    __shared__ float redmx[4], redsm[4];
    __shared__ float part[2][8][16];
    __shared__ float zsum_s[2][16];
    __shared__ float hmp[2][2][64];
    __shared__ float wam3s[16];
    __shared__ float rdens[2];

    int bid = blockIdx.x;
    int b = bid >> 7;
    int n0 = (bid & 127) * 8;
    int t = threadIdx.x;
    int wvid = t >> 6;

    {
        const float4* src = (const float4*)(h_ma + (size_t)b * MM * 64);
        float4* dst = (float4*)hma_s;
        #pragma unroll
        for (int it = 0; it < 8; ++it) dst[t + 256 * it] = src[t + 256 * it];
    }
    if (t < 16) wam3s[t] = wam3[t];
    __syncthreads();

    for (int pp = 0; pp < 4; ++pp) {
        int nsel = t >> 7;
        int m = t & 127;
        int n = n0 + pp * 2 + nsel;
        int bn = b * NN + n;

        // ---- e / u ----
        size_t zbase = ((size_t)bn * MM + m) * 16;
        float4 z0 = *(const float4*)(z + zbase);
        float4 z1 = *(const float4*)(z + zbase + 4);
        float4 z2 = *(const float4*)(z + zbase + 8);
        float4 z3 = *(const float4*)(z + zbase + 12);
        float e = ham1[bn] + hmaam2[b * MM + m];
        e += z0.x*wam3s[0] + z0.y*wam3s[1] + z0.z*wam3s[2] + z0.w*wam3s[3];
        e += z1.x*wam3s[4] + z1.y*wam3s[5] + z1.z*wam3s[6] + z1.w*wam3s[7];
        e += z2.x*wam3s[8] + z2.y*wam3s[9] + z2.z*wam3s[10] + z2.w*wam3s[11];
        e += z3.x*wam3s[12] + z3.y*wam3s[13] + z3.z*wam3s[14] + z3.w*wam3s[15];
        e = e > 0.f ? e : 0.01f * e;
        unsigned long long bits = opmb[(size_t)bn * 2 + (m >> 6)];
        int valid = rmask[bn] | (int)((bits >> (m & 63)) & 1ULL);
        e = valid ? e : -INFINITY;

        float mx = e;
        #pragma unroll
        for (int msk = 32; msk; msk >>= 1) mx = fmaxf(mx, __shfl_xor(mx, msk));
        if ((t & 63) == 0) redmx[wvid] = mx;
        __syncthreads();
        mx = fmaxf(redmx[nsel * 2], redmx[nsel * 2 + 1]);
        float uu = __expf(e - mx);
        u_s[nsel][m] = uu;
        float sv = uu;
        #pragma unroll
        for (int msk = 32; msk; msk >>= 1) sv += __shfl_xor(sv, msk);
        if ((t & 63) == 0) redsm[wvid] = sv;
        __syncthreads();
        float den = redsm[nsel * 2] + redsm[nsel * 2 + 1];
        if (m == 0) rdens[nsel] = 1.f / den;

        // ---- zsum partials: thread = (nsel2, g, i) ----
        {
            int i = t & 15;
            int g = (t >> 4) & 7;
            int ns2 = t >> 7;
            int bn2 = b * NN + n0 + pp * 2 + ns2;
            const float* zr = z + (size_t)bn2 * MM * 16;
            float facc = 0.f;
            #pragma unroll
            for (int k = 0; k < 16; ++k) {
                int mm = g * 16 + k;
                facc += u_s[ns2][mm] * zr[(size_t)mm * 16 + i];
            }
            part[ns2][g][i] = facc;
        }
        // ---- h_ma matvec partials: thread = (nsel3, q, o) ----
        {
            int o = t & 63;
            int q = (t >> 6) & 1;
            int ns3 = t >> 7;
            float acc = 0.f;
            #pragma unroll 8
            for (int k = 0; k < 64; ++k) {
                int mm = q * 64 + k;
                acc += u_s[ns3][mm] * hma_s[mm * 64 + o];
            }
            hmp[ns3][q][o] = acc;
        }
        __syncthreads();
        if (t < 32) {
            int ns = t >> 4, i = t & 15;
            float zs = 0.f;
            #pragma unroll
            for (int g = 0; g < 8; ++g) zs += part[ns][g][i];
            zsum_s[ns][i] = zs;
        }
        __syncthreads();
        if (t < 128) {
            int ns = t >> 6, oo = t & 63;
            int bnf = b * NN + n0 + pp * 2 + ns;
            float he = 0.f;
            #pragma unroll
            for (int i = 0; i < 16; ++i) he += zsum_s[ns][i] * w_edge[i * 64 + oo];
            float val = (hmp[ns][0][oo] + hmp[ns][1][oo] + he) * rdens[ns]
                      + h[(size_t)bnf * 64 + oo];
            h_prime[(size_t)bnf * 128 + 64 + oo] = val;
        }
        __syncthreads();
    }
}

// ================= Kernel 4: MLP + final mask ===============================
// block = 256 (4 waves), 16 rows/block; weights staged in LDS layer-by-layer.
// lane o holds output cols o and o+64; inputs broadcast via readlane shuffles.
__global__ __launch_bounds__(256) void k4_mlp(
    const float* __restrict__ hp, const int* __restrict__ rmask,
    const float* __restrict__ w1, const float* __restrict__ b1,
    const float* __restrict__ w2, const float* __restrict__ b2,
    const float* __restrict__ wo, const float* __restrict__ bo,
    float* __restrict__ out)
{
    __shared__ float wlds[16384];          // 64 KB -> 2 blocks/CU
    int t = threadIdx.x, wv = t >> 6, o = t & 63;
    int row0 = blockIdx.x * 16 + wv * 4;

    float inlo[4], inhi[4];
    #pragma unroll
    for (int r = 0; r < 4; ++r) {
        inlo[r] = hp[(size_t)(row0 + r) * 128 + o];
        inhi[r] = hp[(size_t)(row0 + r) * 128 + 64 + o];
    }

    // ---- stage w1 (64 KB) ----
    {
        const float4* src = (const float4*)w1;
        float4* dst = (float4*)wlds;
        #pragma unroll
        for (int k = 0; k < 16; ++k) dst[k * 256 + t] = src[k * 256 + t];
    }
    __syncthreads();

    // ---- layer 1 ----
    float t1lo[4], t1hi[4];
    {
        float blo = b1[o], bhi = b1[64 + o];
        #pragma unroll
        for (int r = 0; r < 4; ++r) { t1lo[r] = blo; t1hi[r] = bhi; }
        #pragma unroll 8
        for (int i = 0; i < 64; ++i) {
            float wl = wlds[i * 128 + o], wh = wlds[i * 128 + 64 + o];
            #pragma unroll
            for (int r = 0; r < 4; ++r) {
                float xi = __shfl(inlo[r], i);
                t1lo[r] += xi * wl; t1hi[r] += xi * wh;
            }
        }
        #pragma unroll 8
        for (int i = 0; i < 64; ++i) {
            float wl = wlds[(64 + i) * 128 + o], wh = wlds[(64 + i) * 128 + 64 + o];
            #pragma unroll
            for (int r = 0; r < 4; ++r) {
                float xi = __shfl(inhi[r], i);
                t1lo[r] += xi * wl; t1hi[r] += xi * wh;
            }
        }
        #pragma unroll
        for (int r = 0; r < 4; ++r) {
            t1lo[r] = t1lo[r] > 0.f ? t1lo[r] : __expf(t1lo[r]) - 1.f;
            t1hi[r] = t1hi[r] > 0.f ? t1hi[r] : __expf(t1hi[r]) - 1.f;
        }
    }
    __syncthreads();

    // ---- stage w2 (64 KB) ----
    {
        const float4* src = (const float4*)w2;
        float4* dst = (float4*)wlds;
        #pragma unroll
        for (int k = 0; k < 16; ++k) dst[k * 256 + t] = src[k * 256 + t];
    }
    __syncthreads();

    // ---- layer 2 ----
    float t2lo[4], t2hi[4];
    {
        float blo = b2[o], bhi = b2[64 + o];
        #pragma unroll
        for (int r = 0; r < 4; ++r) { t2lo[r] = blo; t2hi[r] = bhi; }
        #pragma unroll 8
        for (int i = 0; i < 64; ++i) {
            float wl = wlds[i * 128 + o], wh = wlds[i * 128 + 64 + o];
            #pragma unroll
            for (int r = 0; r < 4; ++r) {
                float xi = __shfl(t1lo[r], i);
                t2lo[r] += xi * wl; t2hi[r] += xi * wh;
            }
        }
        #pragma unroll 8
        for (int i = 0; i < 64; ++i) {
            float wl = wlds[(64 + i) * 128 + o], wh = wlds[(64 + i) * 128 + 64 + o];
            #pragma unroll
            for (int r = 0; r < 4; ++r) {
                float xi = __shfl(t1hi[r], i);
                t2lo[r] += xi * wl; t2hi[r] += xi * wh;
            }
        }
        #pragma unroll
        for (int r = 0; r < 4; ++r) {
            t2lo[r] = t2lo[r] > 0.f ? t2lo[r] : __expf(t2lo[r]) - 1.f;
            t2hi[r] = t2hi[r] > 0.f ? t2hi[r] : __expf(t2hi[r]) - 1.f;
        }
    }
    __syncthreads();

    // ---- stage wo (32 KB) ----
    {
        const float4* src = (const float4*)wo;
        float4* dst = (float4*)wlds;
        #pragma unroll
        for (int k = 0; k < 8; ++k) dst[k * 256 + t] = src[k * 256 + t];
    }
    __syncthreads();

    // ---- output layer ----
    float acc[4];
    {
        float bov = bo[o];
        #pragma unroll
        for (int r = 0; r < 4; ++r) acc[r] = bov;
        #pragma unroll 8
        for (int i = 0; i < 64; ++i) {
            float wl = wlds[i * 64 + o];
            #pragma unroll
            for (int r = 0; r < 4; ++r) acc[r] += __shfl(t2lo[r], i) * wl;
        }
        #pragma unroll 8
        for (int i = 0; i < 64; ++i) {
            float wl = wlds[(64 + i) * 64 + o];
            #pragma unroll
            for (int r = 0; r < 4; ++r) acc[r] += __shfl(t2hi[r], i) * wl;
        }
    }
    #pragma unroll
    for (int r = 0; r < 4; ++r) {
        int row = row0 + r;
        float v = rmask[row] ? 0.f : acc[r];
        out[(size_t)row * 64 + o] = v;
    }
}

// ============================ launch ========================================
extern "C" void kernel_launch(void* const* d_in, const int* in_sizes, int n_in,
                              void* d_out, int out_size, void* d_ws, size_t ws_size,
                              hipStream_t stream) {
    const float* x      = (const float*)d_in[0];
    const float* y      = (const float*)d_in[1];
    const float* z      = (const float*)d_in[2];
    const int*   op_adj = (const int*)d_in[3];
    const int*   ma_adj = (const int*)d_in[4];
    const int*   opma   = (const int*)d_in[5];
    const float* w_op   = (const float*)d_in[6];
    const float* w_ma   = (const float*)d_in[7];
    const float* w_edge = (const float*)d_in[8];
    const float* att_op = (const float*)d_in[9];
    const float* att_ma = (const float*)d_in[10];
    const float* w1     = (const float*)d_in[11];
    const float* b1     = (const float*)d_in[12];
    const float* w2     = (const float*)d_in[13];
    const float* b2     = (const float*)d_in[14];
    const float* wo     = (const float*)d_in[15];
    const float* bo     = (const float*)d_in[16];
    float* out = (float*)d_out;

    float* ws = (float*)d_ws;
    float* h       = ws + OFF_H;
    float* h_ma    = ws + OFF_HMA;
    float* ha1     = ws + OFF_HA1;
    float* ha2     = ws + OFF_HA2;
    float* ham1    = ws + OFF_HAM1;
    float* hmaam2  = ws + OFF_HMAAM2;
    int*   rmask   = (int*)(ws + OFF_RMASK);
    float* wam3    = ws + OFF_WAM3;
    float* h_prime = ws + OFF_HPRIME;
    unsigned* upack = (unsigned*)(ws + OFF_UPACK);
    unsigned long long* opmb = (unsigned long long*)(ws + OFF_OPMB);

    k1_prep<<<2048 + 256 + 1 + 1088, 256, 0, stream>>>(
        x, y, opma, op_adj, ma_adj, w_op, w_ma, w_edge, att_op, att_ma,
        h, h_ma, ha1, ha2, ham1, hmaam2, rmask, wam3, upack, opmb);

    k2_opatt<<<1024, 256, 0, stream>>>(
        upack, h, ha1, ha2, rmask, h_prime);

    k3_maatt<<<1024, 256, 0, stream>>>(
        z, opmb, h, h_ma, ham1, hmaam2, rmask, wam3, w_edge, h_prime);

    k4_mlp<<<512, 256, 0, stream>>>(
        h_prime, rmask, w1, b1, w2, b2, wo, bo, out);
}

// Round 4
// 114.582 us; speedup vs baseline: 1.0679x; 1.0679x over previous
//
#include <hip/hip_runtime.h>
#include <math.h>

#define BB 8
#define NN 1024
#define MM 128
#define FOUT 64
#define HIDN 128

// ---------------- workspace layout (floats) ----------------
#define OFF_H       0                       // B*N*64 = 524288
#define OFF_HMA     524288                  // B*M*64 = 65536
#define OFF_HA1     589824                  // B*N
#define OFF_HA2     598016                  // B*N
#define OFF_HAM1    606208                  // B*N
#define OFF_HMAAM2  614400                  // B*M
#define OFF_RMASK   615424                  // B*N (ints)
#define OFF_WAM3    623616                  // 16
#define OFF_HPRIME  623632                  // B*N*128 = 1048576
#define OFF_UPACK   1672208                 // B*N*32 u32 = 262144 words
#define OFF_OPMB    1934352                 // B*N*2 u64 = 32768 floats
// total ~1,967,120 floats ~ 7.9 MB

// ================= Kernel 1 (fused): h, h_ma, dots, rmask, opma bits, wam3,
//                   and adjacency bit-pack u = (op|op^T|ma|ma^T)>0 ===========
__global__ __launch_bounds__(256) void k1_prep(
    const float* __restrict__ x, const float* __restrict__ y,
    const int* __restrict__ op_ma_adj,
    const int* __restrict__ op_adj, const int* __restrict__ ma_adj,
    const float* __restrict__ w_op, const float* __restrict__ w_ma,
    const float* __restrict__ w_edge,
    const float* __restrict__ att_op, const float* __restrict__ att_ma,
    float* __restrict__ h, float* __restrict__ h_ma,
    float* __restrict__ ha1, float* __restrict__ ha2, float* __restrict__ ham1,
    float* __restrict__ hmaam2, int* __restrict__ rmask, float* __restrict__ wam3,
    unsigned* __restrict__ upack, unsigned long long* __restrict__ opmb)
{
    __shared__ float wlds[64 * 64];
    int bid = blockIdx.x;
    int t = threadIdx.x;
    int lane = t & 63;
    int wv = t >> 6;

    if (bid < 2048) {
        for (int k = t; k < 4096; k += 256) wlds[k] = w_op[k];
        __syncthreads();
        int row = bid * 4 + wv;                 // b*N + n, 0..8191
        float xv = x[(size_t)row * 64 + lane];
        float acc = 0.f;
        #pragma unroll
        for (int i = 0; i < 64; ++i) {
            float xi = __shfl(xv, i);
            acc += xi * wlds[i * 64 + lane];
        }
        h[(size_t)row * 64 + lane] = acc;
        float d1 = acc * att_op[lane];          // a1
        float d2 = acc * att_op[64 + lane];     // a2
        float d3 = acc * att_ma[lane];          // am1
        #pragma unroll
        for (int m = 32; m; m >>= 1) {
            d1 += __shfl_xor(d1, m);
            d2 += __shfl_xor(d2, m);
            d3 += __shfl_xor(d3, m);
        }
        int v0 = op_ma_adj[(size_t)row * 128 + lane];
        int v1 = op_ma_adj[(size_t)row * 128 + 64 + lane];
        unsigned long long w0 = __ballot(v0 != 0);
        unsigned long long w1 = __ballot(v1 != 0);
        if (lane == 0) {
            ha1[row] = d1; ha2[row] = d2; ham1[row] = d3;
            opmb[row * 2] = w0; opmb[row * 2 + 1] = w1;
            rmask[row] = ((w0 | w1) == 0ULL) ? 1 : 0;
        }
    } else if (bid < 2048 + 256) {
        for (int k = t; k < 4096; k += 256) wlds[k] = w_ma[k];
        __syncthreads();
        int row = (bid - 2048) * 4 + wv;        // b*M + m, 0..1023
        float yv = y[(size_t)row * 64 + lane];
        float acc = 0.f;
        #pragma unroll
        for (int i = 0; i < 64; ++i) {
            float yi = __shfl(yv, i);
            acc += yi * wlds[i * 64 + lane];
        }
        h_ma[(size_t)row * 64 + lane] = acc;
        float d = acc * att_ma[64 + lane];      // am2
        #pragma unroll
        for (int m = 32; m; m >>= 1) d += __shfl_xor(d, m);
        if (lane == 0) hmaam2[row] = d;
    } else if (bid == 2304) {
        if (t < 16) {
            float s = 0.f;
            for (int o = 0; o < 64; ++o) s += w_edge[t * 64 + o] * att_ma[128 + o];
            wam3[t] = s;
        }
    } else {
        // ---- adjacency bit-pack: tile pair (I,J), I<=J, per batch ----
        unsigned* sAB = (unsigned*)wlds;        // [2][64][2]
        int p = bid - 2305;                     // 0..1087
        int b = p / 136;
        int pr = p % 136;
        int I = 0;
        { int rem = pr, cnt = 16;
          while (rem >= cnt) { rem -= cnt; cnt--; I++; }
          pr = rem; }
        int J = I + pr;

        int c = t & 63, hr = (t >> 6) & 1, ts = t >> 7;
        int Ia = ts ? J : I, Ja = ts ? I : J;
        const int* opb = op_adj + (size_t)b * NN * NN + (size_t)(Ia * 64) * NN + Ja * 64;
        const int* mab = ma_adj + (size_t)b * NN * NN + (size_t)(Ia * 64) * NN + Ja * 64;
        unsigned w = 0;
        #pragma unroll 8
        for (int k = 0; k < 32; ++k) {
            int r = hr * 32 + k;
            int aval = opb[(size_t)r * NN + c] | mab[(size_t)r * NN + c];
            w |= (aval ? 1u : 0u) << k;
        }
        sAB[ts * 128 + c * 2 + hr] = w;
        __syncthreads();
        if (t < 128) {
            int r = t & 63, hh = t >> 6;
            int rw = r >> 5, rb = r & 31;
            unsigned dir1 = sAB[128 + r * 2 + hh];   // t2[c][r] bits
            unsigned dir2 = sAB[r * 2 + hh];         // t1[c][r] bits
            unsigned wt1 = 0, wt2 = 0;
            #pragma unroll 8
            for (int k = 0; k < 32; ++k) {
                int cc = hh * 32 + k;
                wt1 |= ((sAB[cc * 2 + rw] >> rb) & 1u) << k;        // t1[r][cc]
                wt2 |= ((sAB[128 + cc * 2 + rw] >> rb) & 1u) << k;  // t2[r][cc]
            }
            upack[((size_t)(b * NN + I * 64 + r)) * 32 + J * 2 + hh] = dir1 | wt1;
            upack[((size_t)(b * NN + J * 64 + r)) * 32 + I * 2 + hh] = dir2 | wt2;
        }
    }
}

// ================= Kernel 2: op attention + h_prime_op ======================
// block = 256 threads, one block per (b, 8-row tile).
__global__ __launch_bounds__(256) void k2_opatt(
    const unsigned* __restrict__ upack,
    const float* __restrict__ h, const float* __restrict__ ha1,
    const float* __restrict__ ha2, const int* __restrict__ rmask,
    float* __restrict__ h_prime)
{
    __shared__ float smem[8 * 1032];
    __shared__ float ha1s[1024];
    __shared__ unsigned uw[8 * 32];
    __shared__ float denom[8];
    int bid = blockIdx.x;
    int b = bid >> 7;
    int i0 = (bid & 127) * 8;
    int t = threadIdx.x;

    uw[t & 255] = upack[((size_t)(b * NN + i0)) * 32 + t];
    for (int k = t; k < 1024; k += 256) ha1s[k] = ha1[b * NN + k];
    __syncthreads();

    // phase 1: masked e, per-row max/sumexp, store unnormalized exp in LDS
    int ii = t >> 5, l = t & 31;
    int i = i0 + ii;
    float ha2i = ha2[b * NN + i];
    unsigned rm = rmask[b * NN + i] ? 0xFFFFFFFFu : 0u;
    float e[32];
    #pragma unroll
    for (int it = 0; it < 32; ++it) {
        int j = l + 32 * it;
        unsigned w = uw[ii * 32 + it] | rm;
        float ev = ha2i + ha1s[j];
        ev = ev > 0.f ? ev : 0.01f * ev;
        e[it] = ((w >> l) & 1u) ? ev : -INFINITY;
    }
    float mx = -INFINITY;
    #pragma unroll
    for (int it = 0; it < 32; ++it) mx = fmaxf(mx, e[it]);
    #pragma unroll
    for (int msk = 16; msk; msk >>= 1) mx = fmaxf(mx, __shfl_xor(mx, msk));
    float s = 0.f;
    #pragma unroll
    for (int it = 0; it < 32; ++it) {
        float u = __expf(e[it] - mx);
        smem[ii * 1032 + l + 32 * it] = u;
        s += u;
    }
    #pragma unroll
    for (int msk = 16; msk; msk >>= 1) s += __shfl_xor(s, msk);
    if (l == 0) denom[ii] = s;
    __syncthreads();

    // phase 2: h_prime_op[k][o] = sum_j u[k][j] * h[b][j][o]
    {
        int wv = t >> 6, o = t & 63;
        float acc[8];
        #pragma unroll
        for (int k = 0; k < 8; ++k) acc[k] = 0.f;
        const float* hb = h + (size_t)b * NN * 64;
        for (int jg = wv * 64; jg < wv * 64 + 64; ++jg) {
            int j = jg * 4;
            float h0 = hb[(size_t)(j + 0) * 64 + o];
            float h1 = hb[(size_t)(j + 1) * 64 + o];
            float h2 = hb[(size_t)(j + 2) * 64 + o];
            float h3 = hb[(size_t)(j + 3) * 64 + o];
            #pragma unroll
            for (int k = 0; k < 8; ++k) {
                float4 u4 = *(const float4*)&smem[k * 1032 + j];
                acc[k] += u4.x * h0 + u4.y * h1 + u4.z * h2 + u4.w * h3;
            }
        }
        __syncthreads();            // everyone done reading u
        #pragma unroll
        for (int k = 0; k < 8; ++k) smem[(wv * 8 + k) * 64 + o] = acc[k];
        __syncthreads();
        int oo = t & 63;
        int k0 = t >> 6;            // handles rows k0 and k0+4
        for (int kk = k0; kk < 8; kk += 4) {
            float v = smem[kk * 64 + oo] + smem[(8 + kk) * 64 + oo]
                    + smem[(16 + kk) * 64 + oo] + smem[(24 + kk) * 64 + oo];
            v /= denom[kk];
            h_prime[((size_t)(b * NN + i0 + kk)) * 128 + oo] = v;
        }
    }
}

// ================= Kernel 3: ma attention + h_prime_ma ======================
// block = 256 threads, handles 8 n's (2 at a time); h_ma staged in LDS.
__global__ __launch_bounds__(256) void k3_maatt(
    const float* __restrict__ z, const unsigned long long* __restrict__ opmb,
    const float* __restrict__ h, const float* __restrict__ h_ma,
    const float* __restrict__ ham1, const float* __restrict__ hmaam2,
    const int* __restrict__ rmask, const float* __restrict__ wam3,
    const float* __restrict__ w_edge, float* __restrict__ h_prime)
{
    __shared__ float hma_s[128 * 64];      // 32 KB
    __shared__ float u_s[2][128];
    __shared__ float redmx[4], redsm[4];
    __shared__ float part[2][8][16];
    __shared__ float zsum_s[2][16];
    __shared__ float hmp[2][2][64];
    __shared__ float wam3s[16];
    __shared__ float rdens[2];

    int bid = blockIdx.x;
    int b = bid >> 7;
    int n0 = (bid & 127) * 8;
    int t = threadIdx.x;
    int wvid = t >> 6;

    {
        const float4* src = (const float4*)(h_ma + (size_t)b * MM * 64);
        float4* dst = (float4*)hma_s;
        #pragma unroll
        for (int it = 0; it < 8; ++it) dst[t + 256 * it] = src[t + 256 * it];
    }
    if (t < 16) wam3s[t] = wam3[t];
    __syncthreads();

    for (int pp = 0; pp < 4; ++pp) {
        int nsel = t >> 7;
        int m = t & 127;
        int n = n0 + pp * 2 + nsel;
        int bn = b * NN + n;

        // ---- e / u ----
        size_t zbase = ((size_t)bn * MM + m) * 16;
        float4 z0 = *(const float4*)(z + zbase);
        float4 z1 = *(const float4*)(z + zbase + 4);
        float4 z2 = *(const float4*)(z + zbase + 8);
        float4 z3 = *(const float4*)(z + zbase + 12);
        float e = ham1[bn] + hmaam2[b * MM + m];
        e += z0.x*wam3s[0] + z0.y*wam3s[1] + z0.z*wam3s[2] + z0.w*wam3s[3];
        e += z1.x*wam3s[4] + z1.y*wam3s[5] + z1.z*wam3s[6] + z1.w*wam3s[7];
        e += z2.x*wam3s[8] + z2.y*wam3s[9] + z2.z*wam3s[10] + z2.w*wam3s[11];
        e += z3.x*wam3s[12] + z3.y*wam3s[13] + z3.z*wam3s[14] + z3.w*wam3s[15];
        e = e > 0.f ? e : 0.01f * e;
        unsigned long long bits = opmb[(size_t)bn * 2 + (m >> 6)];
        int valid = rmask[bn] | (int)((bits >> (m & 63)) & 1ULL);
        e = valid ? e : -INFINITY;

        float mx = e;
        #pragma unroll
        for (int msk = 32; msk; msk >>= 1) mx = fmaxf(mx, __shfl_xor(mx, msk));
        if ((t & 63) == 0) redmx[wvid] = mx;
        __syncthreads();
        mx = fmaxf(redmx[nsel * 2], redmx[nsel * 2 + 1]);
        float uu = __expf(e - mx);
        u_s[nsel][m] = uu;
        float sv = uu;
        #pragma unroll
        for (int msk = 32; msk; msk >>= 1) sv += __shfl_xor(sv, msk);
        if ((t & 63) == 0) redsm[wvid] = sv;
        __syncthreads();
        float den = redsm[nsel * 2] + redsm[nsel * 2 + 1];
        if (m == 0) rdens[nsel] = 1.f / den;

        // ---- zsum partials: thread = (nsel2, g, i) ----
        {
            int i = t & 15;
            int g = (t >> 4) & 7;
            int ns2 = t >> 7;
            int bn2 = b * NN + n0 + pp * 2 + ns2;
            const float* zr = z + (size_t)bn2 * MM * 16;
            float facc = 0.f;
            #pragma unroll
            for (int k = 0; k < 16; ++k) {
                int mm = g * 16 + k;
                facc += u_s[ns2][mm] * zr[(size_t)mm * 16 + i];
            }
            part[ns2][g][i] = facc;
        }
        // ---- h_ma matvec partials: thread = (nsel3, q, o) ----
        {
            int o = t & 63;
            int q = (t >> 6) & 1;
            int ns3 = t >> 7;
            float acc = 0.f;
            #pragma unroll 8
            for (int k = 0; k < 64; ++k) {
                int mm = q * 64 + k;
                acc += u_s[ns3][mm] * hma_s[mm * 64 + o];
            }
            hmp[ns3][q][o] = acc;
        }
        __syncthreads();
        if (t < 32) {
            int ns = t >> 4, i = t & 15;
            float zs = 0.f;
            #pragma unroll
            for (int g = 0; g < 8; ++g) zs += part[ns][g][i];
            zsum_s[ns][i] = zs;
        }
        __syncthreads();
        if (t < 128) {
            int ns = t >> 6, oo = t & 63;
            int bnf = b * NN + n0 + pp * 2 + ns;
            float he = 0.f;
            #pragma unroll
            for (int i = 0; i < 16; ++i) he += zsum_s[ns][i] * w_edge[i * 64 + oo];
            float val = (hmp[ns][0][oo] + hmp[ns][1][oo] + he) * rdens[ns]
                      + h[(size_t)bnf * 64 + oo];
            h_prime[(size_t)bnf * 128 + 64 + oo] = val;
        }
        __syncthreads();
    }
}

// ================= Kernel 4: MLP + final mask ===============================
// block = 256 (4 waves), 8 rows/block, 1024 blocks -> 16 waves/CU.
// No shuffles: inputs/activations in LDS (wave-uniform broadcast reads),
// weights streamed from global (L2-resident), float2-packed.
// Wave wv handles local rows 2wv, 2wv+1; lane o handles cols 2o, 2o+1.
__global__ __launch_bounds__(256) void k4_mlp(
    const float* __restrict__ hp, const int* __restrict__ rmask,
    const float* __restrict__ w1, const float* __restrict__ b1,
    const float* __restrict__ w2, const float* __restrict__ b2,
    const float* __restrict__ wo, const float* __restrict__ bo,
    float* __restrict__ out)
{
    __shared__ float xin[8 * 128];      // 4 KB: input rows, later t2
    __shared__ float tact[8 * 128];     // 4 KB: t1 activations
    int t = threadIdx.x;
    int o = t & 63;
    int wv = t >> 6;
    int row0 = blockIdx.x * 8;
    int lr = wv * 2;                    // local rows lr, lr+1

    // stage 8 input rows (1024 floats = 256 float4), coalesced
    {
        const float4* src = (const float4*)(hp + (size_t)row0 * 128);
        float4* dst = (float4*)xin;
        dst[t] = src[t];
    }
    __syncthreads();

    // ---- layer 1: cols 2o,2o+1 for rows lr,lr+1 ----
    float a0l, a0h, a1l, a1h;
    {
        float2 bb = *(const float2*)&b1[2 * o];
        a0l = bb.x; a0h = bb.y; a1l = bb.x; a1h = bb.y;
        #pragma unroll 8
        for (int i = 0; i < 128; ++i) {
            float2 w = *(const float2*)&w1[i * 128 + 2 * o];
            float x0 = xin[lr * 128 + i];
            float x1 = xin[(lr + 1) * 128 + i];
            a0l += x0 * w.x; a0h += x0 * w.y;
            a1l += x1 * w.x; a1h += x1 * w.y;
        }
        a0l = a0l > 0.f ? a0l : __expf(a0l) - 1.f;
        a0h = a0h > 0.f ? a0h : __expf(a0h) - 1.f;
        a1l = a1l > 0.f ? a1l : __expf(a1l) - 1.f;
        a1h = a1h > 0.f ? a1h : __expf(a1h) - 1.f;
    }
    tact[lr * 128 + 2 * o] = a0l;
    tact[lr * 128 + 2 * o + 1] = a0h;
    tact[(lr + 1) * 128 + 2 * o] = a1l;
    tact[(lr + 1) * 128 + 2 * o + 1] = a1h;
    __syncthreads();

    // ---- layer 2: read tact, write t2 into xin ----
    float c0l, c0h, c1l, c1h;
    {
        float2 bb = *(const float2*)&b2[2 * o];
        c0l = bb.x; c0h = bb.y; c1l = bb.x; c1h = bb.y;
        #pragma unroll 8
        for (int i = 0; i < 128; ++i) {
            float2 w = *(const float2*)&w2[i * 128 + 2 * o];
            float x0 = tact[lr * 128 + i];
            float x1 = tact[(lr + 1) * 128 + i];
            c0l += x0 * w.x; c0h += x0 * w.y;
            c1l += x1 * w.x; c1h += x1 * w.y;
        }
        c0l = c0l > 0.f ? c0l : __expf(c0l) - 1.f;
        c0h = c0h > 0.f ? c0h : __expf(c0h) - 1.f;
        c1l = c1l > 0.f ? c1l : __expf(c1l) - 1.f;
        c1h = c1h > 0.f ? c1h : __expf(c1h) - 1.f;
    }
    xin[lr * 128 + 2 * o] = c0l;
    xin[lr * 128 + 2 * o + 1] = c0h;
    xin[(lr + 1) * 128 + 2 * o] = c1l;
    xin[(lr + 1) * 128 + 2 * o + 1] = c1h;
    __syncthreads();

    // ---- output layer: 64 cols, lane o -> col o ----
    float s0, s1;
    {
        float bov = bo[o];
        s0 = bov; s1 = bov;
        #pragma unroll 8
        for (int i = 0; i < 128; ++i) {
            float w = wo[i * 64 + o];
            s0 += xin[lr * 128 + i] * w;
            s1 += xin[(lr + 1) * 128 + i] * w;
        }
    }
    int g0 = row0 + lr;
    out[(size_t)g0 * 64 + o]       = rmask[g0]     ? 0.f : s0;
    out[(size_t)(g0 + 1) * 64 + o] = rmask[g0 + 1] ? 0.f : s1;
}

// ============================ launch ========================================
extern "C" void kernel_launch(void* const* d_in, const int* in_sizes, int n_in,
                              void* d_out, int out_size, void* d_ws, size_t ws_size,
                              hipStream_t stream) {
    const float* x      = (const float*)d_in[0];
    const float* y      = (const float*)d_in[1];
    const float* z      = (const float*)d_in[2];
    const int*   op_adj = (const int*)d_in[3];
    const int*   ma_adj = (const int*)d_in[4];
    const int*   opma   = (const int*)d_in[5];
    const float* w_op   = (const float*)d_in[6];
    const float* w_ma   = (const float*)d_in[7];
    const float* w_edge = (const float*)d_in[8];
    const float* att_op = (const float*)d_in[9];
    const float* att_ma = (const float*)d_in[10];
    const float* w1     = (const float*)d_in[11];
    const float* b1     = (const float*)d_in[12];
    const float* w2     = (const float*)d_in[13];
    const float* b2     = (const float*)d_in[14];
    const float* wo     = (const float*)d_in[15];
    const float* bo     = (const float*)d_in[16];
    float* out = (float*)d_out;

    float* ws = (float*)d_ws;
    float* h       = ws + OFF_H;
    float* h_ma    = ws + OFF_HMA;
    float* ha1     = ws + OFF_HA1;
    float* ha2     = ws + OFF_HA2;
    float* ham1    = ws + OFF_HAM1;
    float* hmaam2  = ws + OFF_HMAAM2;
    int*   rmask   = (int*)(ws + OFF_RMASK);
    float* wam3    = ws + OFF_WAM3;
    float* h_prime = ws + OFF_HPRIME;
    unsigned* upack = (unsigned*)(ws + OFF_UPACK);
    unsigned long long* opmb = (unsigned long long*)(ws + OFF_OPMB);

    k1_prep<<<2048 + 256 + 1 + 1088, 256, 0, stream>>>(
        x, y, opma, op_adj, ma_adj, w_op, w_ma, w_edge, att_op, att_ma,
        h, h_ma, ha1, ha2, ham1, hmaam2, rmask, wam3, upack, opmb);

    k2_opatt<<<1024, 256, 0, stream>>>(
        upack, h, ha1, ha2, rmask, h_prime);

    k3_maatt<<<1024, 256, 0, stream>>>(
        z, opmb, h, h_ma, ham1, hmaam2, rmask, wam3, w_edge, h_prime);

    k4_mlp<<<1024, 256, 0, stream>>>(
        h_prime, rmask, w1, b1, w2, b2, wo, bo, out);
}

// Round 5
// 91.555 us; speedup vs baseline: 1.3364x; 1.2515x over previous
//
#include <hip/hip_runtime.h>
#include <math.h>

#define BB 8
#define NN 1024
#define MM 128
#define FOUT 64
#define HIDN 128

// ---------------- workspace layout (floats) ----------------
#define OFF_H       0                       // B*N*64 = 524288
#define OFF_HMA     524288                  // B*M*64 = 65536
#define OFF_HA1     589824                  // B*N
#define OFF_HA2     598016                  // B*N
#define OFF_HAM1    606208                  // B*N
#define OFF_HMAAM2  614400                  // B*M
#define OFF_RMASK   615424                  // B*N (ints)
#define OFF_WAM3    623616                  // 16
#define OFF_HPRIME  623632                  // B*N*128 = 1048576
#define OFF_UPACK   1672208                 // B*N*32 u32 = 262144 words
#define OFF_OPMB    1934352                 // B*N*2 u64 = 32768 floats
#define OFF_WT1HI   1967120                 // 128*128 u16 = 8192 floats
#define OFF_WT1LO   1975312
#define OFF_WT2HI   1983504
#define OFF_WT2LO   1991696
#define OFF_WTOHI   1999888                 // 64*128 u16 = 4096 floats
#define OFF_WTOLO   2003984
// total ~2,008,080 floats ~ 8.0 MB

typedef __attribute__((ext_vector_type(8))) short bf16x8;
typedef __attribute__((ext_vector_type(8))) unsigned short u16x8;
typedef __attribute__((ext_vector_type(4))) float f32x4;

__device__ __forceinline__ void splitbf(float v, unsigned short& h, unsigned short& l) {
    unsigned u = __float_as_uint(v);
    unsigned hb = (u + 0x7FFFu + ((u >> 16) & 1u)) >> 16;
    float hf = __uint_as_float(hb << 16);
    float lf = v - hf;
    unsigned ul = __float_as_uint(lf);
    unsigned lb = (ul + 0x7FFFu + ((ul >> 16) & 1u)) >> 16;
    h = (unsigned short)hb; l = (unsigned short)lb;
}

// ================= Kernel 1 (fused): h, h_ma, dots, rmask, opma bits, wam3,
//   adjacency bit-pack u = (op|op^T|ma|ma^T)>0, weight transpose+bf16-split ==
__global__ __launch_bounds__(256) void k1_prep(
    const float* __restrict__ x, const float* __restrict__ y,
    const int* __restrict__ op_ma_adj,
    const int* __restrict__ op_adj, const int* __restrict__ ma_adj,
    const float* __restrict__ w_op, const float* __restrict__ w_ma,
    const float* __restrict__ w_edge,
    const float* __restrict__ att_op, const float* __restrict__ att_ma,
    const float* __restrict__ w1_g, const float* __restrict__ w2_g,
    const float* __restrict__ wo_g,
    float* __restrict__ h, float* __restrict__ h_ma,
    float* __restrict__ ha1, float* __restrict__ ha2, float* __restrict__ ham1,
    float* __restrict__ hmaam2, int* __restrict__ rmask, float* __restrict__ wam3,
    unsigned* __restrict__ upack, unsigned long long* __restrict__ opmb,
    unsigned short* __restrict__ wt1hi, unsigned short* __restrict__ wt1lo,
    unsigned short* __restrict__ wt2hi, unsigned short* __restrict__ wt2lo,
    unsigned short* __restrict__ wtohi, unsigned short* __restrict__ wtolo)
{
    __shared__ float wlds[64 * 64];
    int bid = blockIdx.x;
    int t = threadIdx.x;
    int lane = t & 63;
    int wv = t >> 6;

    if (bid < 2048) {
        for (int k = t; k < 4096; k += 256) wlds[k] = w_op[k];
        __syncthreads();
        int row = bid * 4 + wv;                 // b*N + n, 0..8191
        float xv = x[(size_t)row * 64 + lane];
        float acc = 0.f;
        #pragma unroll
        for (int i = 0; i < 64; ++i) {
            float xi = __shfl(xv, i);
            acc += xi * wlds[i * 64 + lane];
        }
        h[(size_t)row * 64 + lane] = acc;
        float d1 = acc * att_op[lane];          // a1
        float d2 = acc * att_op[64 + lane];     // a2
        float d3 = acc * att_ma[lane];          // am1
        #pragma unroll
        for (int m = 32; m; m >>= 1) {
            d1 += __shfl_xor(d1, m);
            d2 += __shfl_xor(d2, m);
            d3 += __shfl_xor(d3, m);
        }
        int v0 = op_ma_adj[(size_t)row * 128 + lane];
        int v1 = op_ma_adj[(size_t)row * 128 + 64 + lane];
        unsigned long long w0 = __ballot(v0 != 0);
        unsigned long long w1 = __ballot(v1 != 0);
        if (lane == 0) {
            ha1[row] = d1; ha2[row] = d2; ham1[row] = d3;
            opmb[row * 2] = w0; opmb[row * 2 + 1] = w1;
            rmask[row] = ((w0 | w1) == 0ULL) ? 1 : 0;
        }
    } else if (bid < 2048 + 256) {
        for (int k = t; k < 4096; k += 256) wlds[k] = w_ma[k];
        __syncthreads();
        int row = (bid - 2048) * 4 + wv;        // b*M + m, 0..1023
        float yv = y[(size_t)row * 64 + lane];
        float acc = 0.f;
        #pragma unroll
        for (int i = 0; i < 64; ++i) {
            float yi = __shfl(yv, i);
            acc += yi * wlds[i * 64 + lane];
        }
        h_ma[(size_t)row * 64 + lane] = acc;
        float d = acc * att_ma[64 + lane];      // am2
        #pragma unroll
        for (int m = 32; m; m >>= 1) d += __shfl_xor(d, m);
        if (lane == 0) hmaam2[row] = d;
    } else if (bid == 2304) {
        if (t < 16) {
            float s = 0.f;
            for (int o = 0; o < 64; ++o) s += w_edge[t * 64 + o] * att_ma[128 + o];
            wam3[t] = s;
        }
    } else if (bid < 3393) {
        // ---- adjacency bit-pack: tile pair (I,J), I<=J, per batch ----
        unsigned* sAB = (unsigned*)wlds;        // [2][64][2]
        int p = bid - 2305;                     // 0..1087
        int b = p / 136;
        int pr = p % 136;
        int I = 0;
        { int rem = pr, cnt = 16;
          while (rem >= cnt) { rem -= cnt; cnt--; I++; }
          pr = rem; }
        int J = I + pr;

        int c = t & 63, hr = (t >> 6) & 1, ts = t >> 7;
        int Ia = ts ? J : I, Ja = ts ? I : J;
        const int* opb = op_adj + (size_t)b * NN * NN + (size_t)(Ia * 64) * NN + Ja * 64;
        const int* mab = ma_adj + (size_t)b * NN * NN + (size_t)(Ia * 64) * NN + Ja * 64;
        unsigned w = 0;
        #pragma unroll 8
        for (int k = 0; k < 32; ++k) {
            int r = hr * 32 + k;
            int aval = opb[(size_t)r * NN + c] | mab[(size_t)r * NN + c];
            w |= (aval ? 1u : 0u) << k;
        }
        sAB[ts * 128 + c * 2 + hr] = w;
        __syncthreads();
        if (t < 128) {
            int r = t & 63, hh = t >> 6;
            int rw = r >> 5, rb = r & 31;
            unsigned dir1 = sAB[128 + r * 2 + hh];   // t2[c][r] bits
            unsigned dir2 = sAB[r * 2 + hh];         // t1[c][r] bits
            unsigned wt1 = 0, wt2 = 0;
            #pragma unroll 8
            for (int k = 0; k < 32; ++k) {
                int cc = hh * 32 + k;
                wt1 |= ((sAB[cc * 2 + rw] >> rb) & 1u) << k;        // t1[r][cc]
                wt2 |= ((sAB[128 + cc * 2 + rw] >> rb) & 1u) << k;  // t2[r][cc]
            }
            upack[((size_t)(b * NN + I * 64 + r)) * 32 + J * 2 + hh] = dir1 | wt1;
            upack[((size_t)(b * NN + J * 64 + r)) * 32 + I * 2 + hh] = dir2 | wt2;
        }
    } else {
        // ---- MLP weight transpose + bf16 hi/lo split, 32x32 tiles ----
        float (*tls)[33] = (float(*)[33])wlds;
        int p = bid - 3393;                     // 0..39: w1 16, w2 16, wo 8
        const float* src; unsigned short *dhi, *dlo; int KD, CD, tI, tJ;
        if (p < 16)      { src = w1_g; dhi = wt1hi; dlo = wt1lo; KD = 128; CD = 128; tI = p >> 2; tJ = p & 3; }
        else if (p < 32) { src = w2_g; dhi = wt2hi; dlo = wt2lo; KD = 128; CD = 128; tI = (p-16) >> 2; tJ = (p-16) & 3; }
        else             { src = wo_g; dhi = wtohi; dlo = wtolo; KD = 128; CD = 64;  tI = (p-32) >> 1; tJ = (p-32) & 1; }
        int k0 = tI * 32, c0 = tJ * 32;
        #pragma unroll
        for (int it = 0; it < 4; ++it) {
            int r = (t >> 5) + it * 8;
            int c = t & 31;
            tls[r][c] = src[(size_t)(k0 + r) * CD + c0 + c];
        }
        __syncthreads();
        #pragma unroll
        for (int it = 0; it < 4; ++it) {
            int c = (t >> 5) + it * 8;
            int k = t & 31;
            unsigned short hs, ls;
            splitbf(tls[k][c], hs, ls);
            dhi[(size_t)(c0 + c) * KD + k0 + k] = hs;
            dlo[(size_t)(c0 + c) * KD + k0 + k] = ls;
        }
    }
}

// ================= Kernel 2: op attention + h_prime_op ======================
// block = 256 threads, one block per (b, 8-row tile).
__global__ __launch_bounds__(256) void k2_opatt(
    const unsigned* __restrict__ upack,
    const float* __restrict__ h, const float* __restrict__ ha1,
    const float* __restrict__ ha2, const int* __restrict__ rmask,
    float* __restrict__ h_prime)
{
    __shared__ float smem[8 * 1032];
    __shared__ float ha1s[1024];
    __shared__ unsigned uw[8 * 32];
    __shared__ float denom[8];
    int bid = blockIdx.x;
    int b = bid >> 7;
    int i0 = (bid & 127) * 8;
    int t = threadIdx.x;

    uw[t & 255] = upack[((size_t)(b * NN + i0)) * 32 + t];
    for (int k = t; k < 1024; k += 256) ha1s[k] = ha1[b * NN + k];
    __syncthreads();

    // phase 1: masked e, per-row max/sumexp, store unnormalized exp in LDS
    int ii = t >> 5, l = t & 31;
    int i = i0 + ii;
    float ha2i = ha2[b * NN + i];
    unsigned rm = rmask[b * NN + i] ? 0xFFFFFFFFu : 0u;
    float e[32];
    #pragma unroll
    for (int it = 0; it < 32; ++it) {
        int j = l + 32 * it;
        unsigned w = uw[ii * 32 + it] | rm;
        float ev = ha2i + ha1s[j];
        ev = ev > 0.f ? ev : 0.01f * ev;
        e[it] = ((w >> l) & 1u) ? ev : -INFINITY;
    }
    float mx = -INFINITY;
    #pragma unroll
    for (int it = 0; it < 32; ++it) mx = fmaxf(mx, e[it]);
    #pragma unroll
    for (int msk = 16; msk; msk >>= 1) mx = fmaxf(mx, __shfl_xor(mx, msk));
    float s = 0.f;
    #pragma unroll
    for (int it = 0; it < 32; ++it) {
        float u = __expf(e[it] - mx);
        smem[ii * 1032 + l + 32 * it] = u;
        s += u;
    }
    #pragma unroll
    for (int msk = 16; msk; msk >>= 1) s += __shfl_xor(s, msk);
    if (l == 0) denom[ii] = s;
    __syncthreads();

    // phase 2: h_prime_op[k][o] = sum_j u[k][j] * h[b][j][o]
    {
        int wv = t >> 6, o = t & 63;
        float acc[8];
        #pragma unroll
        for (int k = 0; k < 8; ++k) acc[k] = 0.f;
        const float* hb = h + (size_t)b * NN * 64;
        for (int jg = wv * 64; jg < wv * 64 + 64; ++jg) {
            int j = jg * 4;
            float h0 = hb[(size_t)(j + 0) * 64 + o];
            float h1 = hb[(size_t)(j + 1) * 64 + o];
            float h2 = hb[(size_t)(j + 2) * 64 + o];
            float h3 = hb[(size_t)(j + 3) * 64 + o];
            #pragma unroll
            for (int k = 0; k < 8; ++k) {
                float4 u4 = *(const float4*)&smem[k * 1032 + j];
                acc[k] += u4.x * h0 + u4.y * h1 + u4.z * h2 + u4.w * h3;
            }
        }
        __syncthreads();            // everyone done reading u
        #pragma unroll
        for (int k = 0; k < 8; ++k) smem[(wv * 8 + k) * 64 + o] = acc[k];
        __syncthreads();
        int oo = t & 63;
        int k0 = t >> 6;            // handles rows k0 and k0+4
        for (int kk = k0; kk < 8; kk += 4) {
            float v = smem[kk * 64 + oo] + smem[(8 + kk) * 64 + oo]
                    + smem[(16 + kk) * 64 + oo] + smem[(24 + kk) * 64 + oo];
            v /= denom[kk];
            h_prime[((size_t)(b * NN + i0 + kk)) * 128 + oo] = v;
        }
    }
}

// ================= Kernel 3: ma attention + h_prime_ma ======================
// block = 256 threads, handles 8 n's (2 at a time); h_ma staged in LDS.
__global__ __launch_bounds__(256) void k3_maatt(
    const float* __restrict__ z, const unsigned long long* __restrict__ opmb,
    const float* __restrict__ h, const float* __restrict__ h_ma,
    const float* __restrict__ ham1, const float* __restrict__ hmaam2,
    const int* __restrict__ rmask, const float* __restrict__ wam3,
    const float* __restrict__ w_edge, float* __restrict__ h_prime)
{
    __shared__ float hma_s[128 * 64];      // 32 KB
    __shared__ float u_s[2][128];
    __shared__ float redmx[4], redsm[4];
    __shared__ float part[2][8][16];
    __shared__ float zsum_s[2][16];
    __shared__ float hmp[2][2][64];
    __shared__ float wam3s[16];
    __shared__ float rdens[2];

    int bid = blockIdx.x;
    int b = bid >> 7;
    int n0 = (bid & 127) * 8;
    int t = threadIdx.x;
    int wvid = t >> 6;

    {
        const float4* src = (const float4*)(h_ma + (size_t)b * MM * 64);
        float4* dst = (float4*)hma_s;
        #pragma unroll
        for (int it = 0; it < 8; ++it) dst[t + 256 * it] = src[t + 256 * it];
    }
    if (t < 16) wam3s[t] = wam3[t];
    __syncthreads();

    for (int pp = 0; pp < 4; ++pp) {
        int nsel = t >> 7;
        int m = t & 127;
        int n = n0 + pp * 2 + nsel;
        int bn = b * NN + n;

        // ---- e / u ----
        size_t zbase = ((size_t)bn * MM + m) * 16;
        float4 z0 = *(const float4*)(z + zbase);
        float4 z1 = *(const float4*)(z + zbase + 4);
        float4 z2 = *(const float4*)(z + zbase + 8);
        float4 z3 = *(const float4*)(z + zbase + 12);
        float e = ham1[bn] + hmaam2[b * MM + m];
        e += z0.x*wam3s[0] + z0.y*wam3s[1] + z0.z*wam3s[2] + z0.w*wam3s[3];
        e += z1.x*wam3s[4] + z1.y*wam3s[5] + z1.z*wam3s[6] + z1.w*wam3s[7];
        e += z2.x*wam3s[8] + z2.y*wam3s[9] + z2.z*wam3s[10] + z2.w*wam3s[11];
        e += z3.x*wam3s[12] + z3.y*wam3s[13] + z3.z*wam3s[14] + z3.w*wam3s[15];
        e = e > 0.f ? e : 0.01f * e;
        unsigned long long bits = opmb[(size_t)bn * 2 + (m >> 6)];
        int valid = rmask[bn] | (int)((bits >> (m & 63)) & 1ULL);
        e = valid ? e : -INFINITY;

        float mx = e;
        #pragma unroll
        for (int msk = 32; msk; msk >>= 1) mx = fmaxf(mx, __shfl_xor(mx, msk));
        if ((t & 63) == 0) redmx[wvid] = mx;
        __syncthreads();
        mx = fmaxf(redmx[nsel * 2], redmx[nsel * 2 + 1]);
        float uu = __expf(e - mx);
        u_s[nsel][m] = uu;
        float sv = uu;
        #pragma unroll
        for (int msk = 32; msk; msk >>= 1) sv += __shfl_xor(sv, msk);
        if ((t & 63) == 0) redsm[wvid] = sv;
        __syncthreads();
        float den = redsm[nsel * 2] + redsm[nsel * 2 + 1];
        if (m == 0) rdens[nsel] = 1.f / den;

        // ---- zsum partials: thread = (nsel2, g, i) ----
        {
            int i = t & 15;
            int g = (t >> 4) & 7;
            int ns2 = t >> 7;
            int bn2 = b * NN + n0 + pp * 2 + ns2;
            const float* zr = z + (size_t)bn2 * MM * 16;
            float facc = 0.f;
            #pragma unroll
            for (int k = 0; k < 16; ++k) {
                int mm = g * 16 + k;
                facc += u_s[ns2][mm] * zr[(size_t)mm * 16 + i];
            }
            part[ns2][g][i] = facc;
        }
        // ---- h_ma matvec partials: thread = (nsel3, q, o) ----
        {
            int o = t & 63;
            int q = (t >> 6) & 1;
            int ns3 = t >> 7;
            float acc = 0.f;
            #pragma unroll 8
            for (int k = 0; k < 64; ++k) {
                int mm = q * 64 + k;
                acc += u_s[ns3][mm] * hma_s[mm * 64 + o];
            }
            hmp[ns3][q][o] = acc;
        }
        __syncthreads();
        if (t < 32) {
            int ns = t >> 4, i = t & 15;
            float zs = 0.f;
            #pragma unroll
            for (int g = 0; g < 8; ++g) zs += part[ns][g][i];
            zsum_s[ns][i] = zs;
        }
        __syncthreads();
        if (t < 128) {
            int ns = t >> 6, oo = t & 63;
            int bnf = b * NN + n0 + pp * 2 + ns;
            float he = 0.f;
            #pragma unroll
            for (int i = 0; i < 16; ++i) he += zsum_s[ns][i] * w_edge[i * 64 + oo];
            float val = (hmp[ns][0][oo] + hmp[ns][1][oo] + he) * rdens[ns]
                      + h[(size_t)bnf * 64 + oo];
            h_prime[(size_t)bnf * 128 + 64 + oo] = val;
        }
        __syncthreads();
    }
}

// ================= Kernel 4: MLP via MFMA (bf16 hi/lo split) ================
// block = 256 (4 waves), 16 rows/block, grid 512. Per layer: C = A@W with
// A frags from LDS planes, W frags from pre-transposed global bf16 planes.
// 3 MFMAs per k-step (hihi + hilo + lohi) ~ f32 accuracy.
__global__ __launch_bounds__(256) void k4_mlp(
    const float* __restrict__ hp, const int* __restrict__ rmask,
    const unsigned short* __restrict__ wt1hi, const unsigned short* __restrict__ wt1lo,
    const unsigned short* __restrict__ wt2hi, const unsigned short* __restrict__ wt2lo,
    const unsigned short* __restrict__ wtohi, const unsigned short* __restrict__ wtolo,
    const float* __restrict__ b1, const float* __restrict__ b2,
    const float* __restrict__ bo, float* __restrict__ out)
{
    __shared__ __align__(16) unsigned short Ahi0[16 * 136];
    __shared__ __align__(16) unsigned short Alo0[16 * 136];
    __shared__ __align__(16) unsigned short Ahi1[16 * 136];
    __shared__ __align__(16) unsigned short Alo1[16 * 136];
    __shared__ int rml[16];
    int t = threadIdx.x;
    int lane = t & 63;
    int wv = t >> 6;
    int row0 = blockIdx.x * 16;

    // ---- stage input rows, split to hi/lo planes ----
    {
        int r = t >> 4;                 // 0..15
        int cg = (t & 15) * 8;          // 8-elem chunk
        const float* src = hp + (size_t)(row0 + r) * 128 + cg;
        float4 v0 = *(const float4*)src;
        float4 v1 = *(const float4*)(src + 4);
        float xs[8] = {v0.x, v0.y, v0.z, v0.w, v1.x, v1.y, v1.z, v1.w};
        u16x8 hv, lv;
        #pragma unroll
        for (int j = 0; j < 8; ++j) {
            unsigned short hs, ls;
            splitbf(xs[j], hs, ls);
            hv[j] = hs; lv[j] = ls;
        }
        *(u16x8*)&Ahi0[r * 136 + cg] = hv;
        *(u16x8*)&Alo0[r * 136 + cg] = lv;
        if (t < 16) rml[t] = rmask[row0 + t];
    }
    __syncthreads();

    int arow = lane & 15;
    int kg = lane >> 4;                 // 0..3
    int aoff = arow * 136 + kg * 8;

    // ---- layer 1: A0 -> A1 ----
    {
        bf16x8 ah[4], al[4];
        #pragma unroll
        for (int ks = 0; ks < 4; ++ks) {
            ah[ks] = *(const bf16x8*)&Ahi0[aoff + ks * 32];
            al[ks] = *(const bf16x8*)&Alo0[aoff + ks * 32];
        }
        #pragma unroll
        for (int q = 0; q < 2; ++q) {
            int ct = wv + q * 4;
            int col = ct * 16 + arow;
            const unsigned short* wh = wt1hi + (size_t)col * 128 + kg * 8;
            const unsigned short* wl = wt1lo + (size_t)col * 128 + kg * 8;
            f32x4 acc = {0.f, 0.f, 0.f, 0.f};
            #pragma unroll
            for (int ks = 0; ks < 4; ++ks) {
                bf16x8 bh = *(const bf16x8*)&wh[ks * 32];
                bf16x8 bl = *(const bf16x8*)&wl[ks * 32];
                acc = __builtin_amdgcn_mfma_f32_16x16x32_bf16(ah[ks], bh, acc, 0, 0, 0);
                acc = __builtin_amdgcn_mfma_f32_16x16x32_bf16(al[ks], bh, acc, 0, 0, 0);
                acc = __builtin_amdgcn_mfma_f32_16x16x32_bf16(ah[ks], bl, acc, 0, 0, 0);
            }
            float bb = b1[col];
            #pragma unroll
            for (int r = 0; r < 4; ++r) {
                int row = kg * 4 + r;
                float v = acc[r] + bb;
                v = v > 0.f ? v : __expf(v) - 1.f;
                unsigned short hs, ls;
                splitbf(v, hs, ls);
                Ahi1[row * 136 + col] = hs;
                Alo1[row * 136 + col] = ls;
            }
        }
    }
    __syncthreads();

    // ---- layer 2: A1 -> A0 ----
    {
        bf16x8 ah[4], al[4];
        #pragma unroll
        for (int ks = 0; ks < 4; ++ks) {
            ah[ks] = *(const bf16x8*)&Ahi1[aoff + ks * 32];
            al[ks] = *(const bf16x8*)&Alo1[aoff + ks * 32];
        }
        #pragma unroll
        for (int q = 0; q < 2; ++q) {
            int ct = wv + q * 4;
            int col = ct * 16 + arow;
            const unsigned short* wh = wt2hi + (size_t)col * 128 + kg * 8;
            const unsigned short* wl = wt2lo + (size_t)col * 128 + kg * 8;
            f32x4 acc = {0.f, 0.f, 0.f, 0.f};
            #pragma unroll
            for (int ks = 0; ks < 4; ++ks) {
                bf16x8 bh = *(const bf16x8*)&wh[ks * 32];
                bf16x8 bl = *(const bf16x8*)&wl[ks * 32];
                acc = __builtin_amdgcn_mfma_f32_16x16x32_bf16(ah[ks], bh, acc, 0, 0, 0);
                acc = __builtin_amdgcn_mfma_f32_16x16x32_bf16(al[ks], bh, acc, 0, 0, 0);
                acc = __builtin_amdgcn_mfma_f32_16x16x32_bf16(ah[ks], bl, acc, 0, 0, 0);
            }
            float bb = b2[col];
            #pragma unroll
            for (int r = 0; r < 4; ++r) {
                int row = kg * 4 + r;
                float v = acc[r] + bb;
                v = v > 0.f ? v : __expf(v) - 1.f;
                unsigned short hs, ls;
                splitbf(v, hs, ls);
                Ahi0[row * 136 + col] = hs;
                Alo0[row * 136 + col] = ls;
            }
        }
    }
    __syncthreads();

    // ---- layer 3 (output): A0 @ WO, + bo, rmask zero, store ----
    {
        bf16x8 ah[4], al[4];
        #pragma unroll
        for (int ks = 0; ks < 4; ++ks) {
            ah[ks] = *(const bf16x8*)&Ahi0[aoff + ks * 32];
            al[ks] = *(const bf16x8*)&Alo0[aoff + ks * 32];
        }
        int ct = wv;                    // 4 coltiles of 16 -> 64 cols
        int col = ct * 16 + arow;
        const unsigned short* wh = wtohi + (size_t)col * 128 + kg * 8;
        const unsigned short* wl = wtolo + (size_t)col * 128 + kg * 8;
        f32x4 acc = {0.f, 0.f, 0.f, 0.f};
        #pragma unroll
        for (int ks = 0; ks < 4; ++ks) {
            bf16x8 bh = *(const bf16x8*)&wh[ks * 32];
            bf16x8 bl = *(const bf16x8*)&wl[ks * 32];
            acc = __builtin_amdgcn_mfma_f32_16x16x32_bf16(ah[ks], bh, acc, 0, 0, 0);
            acc = __builtin_amdgcn_mfma_f32_16x16x32_bf16(al[ks], bh, acc, 0, 0, 0);
            acc = __builtin_amdgcn_mfma_f32_16x16x32_bf16(ah[ks], bl, acc, 0, 0, 0);
        }
        float bb = bo[col];
        #pragma unroll
        for (int r = 0; r < 4; ++r) {
            int row = kg * 4 + r;
            float v = acc[r] + bb;
            out[(size_t)(row0 + row) * 64 + col] = rml[row] ? 0.f : v;
        }
    }
}

// ============================ launch ========================================
extern "C" void kernel_launch(void* const* d_in, const int* in_sizes, int n_in,
                              void* d_out, int out_size, void* d_ws, size_t ws_size,
                              hipStream_t stream) {
    const float* x      = (const float*)d_in[0];
    const float* y      = (const float*)d_in[1];
    const float* z      = (const float*)d_in[2];
    const int*   op_adj = (const int*)d_in[3];
    const int*   ma_adj = (const int*)d_in[4];
    const int*   opma   = (const int*)d_in[5];
    const float* w_op   = (const float*)d_in[6];
    const float* w_ma   = (const float*)d_in[7];
    const float* w_edge = (const float*)d_in[8];
    const float* att_op = (const float*)d_in[9];
    const float* att_ma = (const float*)d_in[10];
    const float* w1     = (const float*)d_in[11];
    const float* b1     = (const float*)d_in[12];
    const float* w2     = (const float*)d_in[13];
    const float* b2     = (const float*)d_in[14];
    const float* wo     = (const float*)d_in[15];
    const float* bo     = (const float*)d_in[16];
    float* out = (float*)d_out;

    float* ws = (float*)d_ws;
    float* h       = ws + OFF_H;
    float* h_ma    = ws + OFF_HMA;
    float* ha1     = ws + OFF_HA1;
    float* ha2     = ws + OFF_HA2;
    float* ham1    = ws + OFF_HAM1;
    float* hmaam2  = ws + OFF_HMAAM2;
    int*   rmask   = (int*)(ws + OFF_RMASK);
    float* wam3    = ws + OFF_WAM3;
    float* h_prime = ws + OFF_HPRIME;
    unsigned* upack = (unsigned*)(ws + OFF_UPACK);
    unsigned long long* opmb = (unsigned long long*)(ws + OFF_OPMB);
    unsigned short* wt1hi = (unsigned short*)(ws + OFF_WT1HI);
    unsigned short* wt1lo = (unsigned short*)(ws + OFF_WT1LO);
    unsigned short* wt2hi = (unsigned short*)(ws + OFF_WT2HI);
    unsigned short* wt2lo = (unsigned short*)(ws + OFF_WT2LO);
    unsigned short* wtohi = (unsigned short*)(ws + OFF_WTOHI);
    unsigned short* wtolo = (unsigned short*)(ws + OFF_WTOLO);

    k1_prep<<<2048 + 256 + 1 + 1088 + 40, 256, 0, stream>>>(
        x, y, opma, op_adj, ma_adj, w_op, w_ma, w_edge, att_op, att_ma,
        w1, w2, wo,
        h, h_ma, ha1, ha2, ham1, hmaam2, rmask, wam3, upack, opmb,
        wt1hi, wt1lo, wt2hi, wt2lo, wtohi, wtolo);

    k2_opatt<<<1024, 256, 0, stream>>>(
        upack, h, ha1, ha2, rmask, h_prime);

    k3_maatt<<<1024, 256, 0, stream>>>(
        z, opmb, h, h_ma, ham1, hmaam2, rmask, wam3, w_edge, h_prime);

    k4_mlp<<<512, 256, 0, stream>>>(
        h_prime, rmask, wt1hi, wt1lo, wt2hi, wt2lo, wtohi, wtolo,
        b1, b2, bo, out);
}

// Round 6
// 87.439 us; speedup vs baseline: 1.3993x; 1.0471x over previous
//
#include <hip/hip_runtime.h>
#include <math.h>

#define BB 8
#define NN 1024
#define MM 128
#define FOUT 64
#define HIDN 128

// ---------------- workspace layout (floats) ----------------
#define OFF_H       0                       // B*N*64 = 524288
#define OFF_HMA     524288                  // B*M*64 = 65536
#define OFF_HA1     589824                  // B*N
#define OFF_HA2     598016                  // B*N
#define OFF_HAM1    606208                  // B*N
#define OFF_HMAAM2  614400                  // B*M
#define OFF_RMASK   615424                  // B*N (ints)
#define OFF_WAM3    623616                  // 16
#define OFF_HPRIME  623632                  // B*N*128 = 1048576
#define OFF_UPACK   1672208                 // B*N*32 u32 = 262144 words
#define OFF_OPMB    1934352                 // B*N*2 u64 = 32768 floats
#define OFF_WT1HI   1967120                 // 128*128 u16 = 8192 floats
#define OFF_WT1LO   1975312
#define OFF_WT2HI   1983504
#define OFF_WT2LO   1991696
#define OFF_WTOHI   1999888                 // 64*128 u16 = 4096 floats
#define OFF_WTOLO   2003984
#define OFF_HTHI    2008080                 // B*64*1024 u16 = 262144 floats
#define OFF_HTLO    2270224
// total ~2,532,368 floats ~ 10.1 MB

typedef __attribute__((ext_vector_type(8))) short bf16x8;
typedef __attribute__((ext_vector_type(8))) unsigned short u16x8;
typedef __attribute__((ext_vector_type(4))) float f32x4;

__device__ __forceinline__ void splitbf(float v, unsigned short& h, unsigned short& l) {
    unsigned u = __float_as_uint(v);
    unsigned hb = (u + 0x7FFFu + ((u >> 16) & 1u)) >> 16;
    float hf = __uint_as_float(hb << 16);
    float lf = v - hf;
    unsigned ul = __float_as_uint(lf);
    unsigned lb = (ul + 0x7FFFu + ((ul >> 16) & 1u)) >> 16;
    h = (unsigned short)hb; l = (unsigned short)lb;
}

// ================= Kernel 1 (fused): h (+bf16 transposed planes), h_ma, dots,
//   rmask, opma bits, wam3, adjacency bit-pack, MLP weight transpose+split ===
__global__ __launch_bounds__(256) void k1_prep(
    const float* __restrict__ x, const float* __restrict__ y,
    const int* __restrict__ op_ma_adj,
    const int* __restrict__ op_adj, const int* __restrict__ ma_adj,
    const float* __restrict__ w_op, const float* __restrict__ w_ma,
    const float* __restrict__ w_edge,
    const float* __restrict__ att_op, const float* __restrict__ att_ma,
    const float* __restrict__ w1_g, const float* __restrict__ w2_g,
    const float* __restrict__ wo_g,
    float* __restrict__ h, float* __restrict__ h_ma,
    float* __restrict__ ha1, float* __restrict__ ha2, float* __restrict__ ham1,
    float* __restrict__ hmaam2, int* __restrict__ rmask, float* __restrict__ wam3,
    unsigned* __restrict__ upack, unsigned long long* __restrict__ opmb,
    unsigned short* __restrict__ wt1hi, unsigned short* __restrict__ wt1lo,
    unsigned short* __restrict__ wt2hi, unsigned short* __restrict__ wt2lo,
    unsigned short* __restrict__ wtohi, unsigned short* __restrict__ wtolo,
    unsigned short* __restrict__ hthi, unsigned short* __restrict__ htlo)
{
    __shared__ float wlds[64 * 64];
    int bid = blockIdx.x;
    int t = threadIdx.x;
    int lane = t & 63;
    int wv = t >> 6;

    if (bid < 2048) {
        for (int k = t; k < 4096; k += 256) wlds[k] = w_op[k];
        __syncthreads();
        int row = bid * 4 + wv;                 // b*N + n, 0..8191
        float xv = x[(size_t)row * 64 + lane];
        float acc = 0.f;
        #pragma unroll
        for (int i = 0; i < 64; ++i) {
            float xi = __shfl(xv, i);
            acc += xi * wlds[i * 64 + lane];
        }
        h[(size_t)row * 64 + lane] = acc;
        // transposed bf16 hi/lo planes for k2's MFMA B operand
        {
            unsigned short hs, ls;
            splitbf(acc, hs, ls);
            size_t tb = ((size_t)((row >> 10) * 64 + lane)) * 1024 + (row & 1023);
            hthi[tb] = hs; htlo[tb] = ls;
        }
        float d1 = acc * att_op[lane];          // a1
        float d2 = acc * att_op[64 + lane];     // a2
        float d3 = acc * att_ma[lane];          // am1
        #pragma unroll
        for (int m = 32; m; m >>= 1) {
            d1 += __shfl_xor(d1, m);
            d2 += __shfl_xor(d2, m);
            d3 += __shfl_xor(d3, m);
        }
        int v0 = op_ma_adj[(size_t)row * 128 + lane];
        int v1 = op_ma_adj[(size_t)row * 128 + 64 + lane];
        unsigned long long w0 = __ballot(v0 != 0);
        unsigned long long w1 = __ballot(v1 != 0);
        if (lane == 0) {
            ha1[row] = d1; ha2[row] = d2; ham1[row] = d3;
            opmb[row * 2] = w0; opmb[row * 2 + 1] = w1;
            rmask[row] = ((w0 | w1) == 0ULL) ? 1 : 0;
        }
    } else if (bid < 2048 + 256) {
        for (int k = t; k < 4096; k += 256) wlds[k] = w_ma[k];
        __syncthreads();
        int row = (bid - 2048) * 4 + wv;        // b*M + m, 0..1023
        float yv = y[(size_t)row * 64 + lane];
        float acc = 0.f;
        #pragma unroll
        for (int i = 0; i < 64; ++i) {
            float yi = __shfl(yv, i);
            acc += yi * wlds[i * 64 + lane];
        }
        h_ma[(size_t)row * 64 + lane] = acc;
        float d = acc * att_ma[64 + lane];      // am2
        #pragma unroll
        for (int m = 32; m; m >>= 1) d += __shfl_xor(d, m);
        if (lane == 0) hmaam2[row] = d;
    } else if (bid == 2304) {
        if (t < 16) {
            float s = 0.f;
            for (int o = 0; o < 64; ++o) s += w_edge[t * 64 + o] * att_ma[128 + o];
            wam3[t] = s;
        }
    } else if (bid < 3393) {
        // ---- adjacency bit-pack: tile pair (I,J), I<=J, per batch ----
        unsigned* sAB = (unsigned*)wlds;        // [2][64][2]
        int p = bid - 2305;                     // 0..1087
        int b = p / 136;
        int pr = p % 136;
        int I = 0;
        { int rem = pr, cnt = 16;
          while (rem >= cnt) { rem -= cnt; cnt--; I++; }
          pr = rem; }
        int J = I + pr;

        int c = t & 63, hr = (t >> 6) & 1, ts = t >> 7;
        int Ia = ts ? J : I, Ja = ts ? I : J;
        const int* opb = op_adj + (size_t)b * NN * NN + (size_t)(Ia * 64) * NN + Ja * 64;
        const int* mab = ma_adj + (size_t)b * NN * NN + (size_t)(Ia * 64) * NN + Ja * 64;
        unsigned w = 0;
        #pragma unroll 8
        for (int k = 0; k < 32; ++k) {
            int r = hr * 32 + k;
            int aval = opb[(size_t)r * NN + c] | mab[(size_t)r * NN + c];
            w |= (aval ? 1u : 0u) << k;
        }
        sAB[ts * 128 + c * 2 + hr] = w;
        __syncthreads();
        if (t < 128) {
            int r = t & 63, hh = t >> 6;
            int rw = r >> 5, rb = r & 31;
            unsigned dir1 = sAB[128 + r * 2 + hh];   // t2[c][r] bits
            unsigned dir2 = sAB[r * 2 + hh];         // t1[c][r] bits
            unsigned wt1 = 0, wt2 = 0;
            #pragma unroll 8
            for (int k = 0; k < 32; ++k) {
                int cc = hh * 32 + k;
                wt1 |= ((sAB[cc * 2 + rw] >> rb) & 1u) << k;        // t1[r][cc]
                wt2 |= ((sAB[128 + cc * 2 + rw] >> rb) & 1u) << k;  // t2[r][cc]
            }
            upack[((size_t)(b * NN + I * 64 + r)) * 32 + J * 2 + hh] = dir1 | wt1;
            upack[((size_t)(b * NN + J * 64 + r)) * 32 + I * 2 + hh] = dir2 | wt2;
        }
    } else {
        // ---- MLP weight transpose + bf16 hi/lo split, 32x32 tiles ----
        float (*tls)[33] = (float(*)[33])wlds;
        int p = bid - 3393;                     // 0..39: w1 16, w2 16, wo 8
        const float* src; unsigned short *dhi, *dlo; int KD, CD, tI, tJ;
        if (p < 16)      { src = w1_g; dhi = wt1hi; dlo = wt1lo; KD = 128; CD = 128; tI = p >> 2; tJ = p & 3; }
        else if (p < 32) { src = w2_g; dhi = wt2hi; dlo = wt2lo; KD = 128; CD = 128; tI = (p-16) >> 2; tJ = (p-16) & 3; }
        else             { src = wo_g; dhi = wtohi; dlo = wtolo; KD = 128; CD = 64;  tI = (p-32) >> 1; tJ = (p-32) & 1; }
        int k0 = tI * 32, c0 = tJ * 32;
        #pragma unroll
        for (int it = 0; it < 4; ++it) {
            int r = (t >> 5) + it * 8;
            int c = t & 31;
            tls[r][c] = src[(size_t)(k0 + r) * CD + c0 + c];
        }
        __syncthreads();
        #pragma unroll
        for (int it = 0; it < 4; ++it) {
            int c = (t >> 5) + it * 8;
            int k = t & 31;
            unsigned short hs, ls;
            splitbf(tls[k][c], hs, ls);
            dhi[(size_t)(c0 + c) * KD + k0 + k] = hs;
            dlo[(size_t)(c0 + c) * KD + k0 + k] = ls;
        }
    }
}

// ================= Kernel 2: op attention + h_prime_op via MFMA =============
// block = 256 (4 waves), 16 rows/block, grid 512. Phase 1: e/max/exp on VALU,
// P stored as bf16 in LDS (XOR-swizzled). Phase 2: P @ (h_hi + h_lo) MFMA.
__global__ __launch_bounds__(256) void k2_opatt(
    const unsigned* __restrict__ upack,
    const unsigned short* __restrict__ hthi,
    const unsigned short* __restrict__ htlo,
    const float* __restrict__ ha1, const float* __restrict__ ha2,
    const int* __restrict__ rmask, float* __restrict__ h_prime)
{
    __shared__ __align__(16) unsigned short Pl[16 * 1024];   // 32 KB
    __shared__ float ha1s[1024];
    __shared__ unsigned uws[512];
    __shared__ float rdeninv[16];
    int bid = blockIdx.x;
    int b = bid >> 6;
    int i0 = (bid & 63) << 4;
    int t = threadIdx.x;

    {
        size_t ub = (size_t)(b * NN + i0) * 32;
        uws[t] = upack[ub + t];
        uws[t + 256] = upack[ub + t + 256];
    }
    ha1s[t] = ha1[b * NN + t];
    ha1s[t + 256] = ha1[b * NN + t + 256];
    ha1s[t + 512] = ha1[b * NN + t + 512];
    ha1s[t + 768] = ha1[b * NN + t + 768];
    __syncthreads();

    // ---- phase 1: P[row][j] = exp(masked leaky(ha2_i + ha1_j) - rowmax) ----
    {
        int row = t >> 4, q = t & 15;
        int bn = b * NN + i0 + row;
        float ha2i = ha2[bn];
        unsigned rm = rmask[bn] ? 0xFFFFFFFFu : 0u;

        float mx = -INFINITY;
        #pragma unroll 8
        for (int jj = 0; jj < 64; ++jj) {
            int j = q + (jj << 4);
            float ev = ha2i + ha1s[j];
            ev = ev > 0.f ? ev : 0.01f * ev;
            unsigned w = uws[row * 32 + (j >> 5)] | rm;
            if ((w >> (j & 31)) & 1u) mx = fmaxf(mx, ev);
        }
        #pragma unroll
        for (int m = 1; m < 16; m <<= 1) mx = fmaxf(mx, __shfl_xor(mx, m));

        float s = 0.f;
        #pragma unroll 4
        for (int jj = 0; jj < 64; ++jj) {
            int j = q + (jj << 4);
            float ev = ha2i + ha1s[j];
            ev = ev > 0.f ? ev : 0.01f * ev;
            unsigned w = uws[row * 32 + (j >> 5)] | rm;
            float u = ((w >> (j & 31)) & 1u) ? __expf(ev - mx) : 0.f;
            s += u;
            unsigned ub = __float_as_uint(u);
            unsigned short pb = (unsigned short)((ub + 0x7FFFu + ((ub >> 16) & 1u)) >> 16);
            unsigned byteoff = ((unsigned)(row * 2048 + j * 2)) ^ ((unsigned)((row & 7) << 4));
            *(unsigned short*)((char*)Pl + byteoff) = pb;
        }
        #pragma unroll
        for (int m = 1; m < 16; m <<= 1) s += __shfl_xor(s, m);
        if (q == 0) rdeninv[row] = 1.f / s;
    }
    __syncthreads();

    // ---- phase 2: C = P @ h  (A from LDS swizzled, B from h_t hi/lo) ----
    {
        int lane = t & 63, wvv = t >> 6;
        int arow = lane & 15, kg = lane >> 4;
        int col = wvv * 16 + arow;
        const unsigned short* bhp = hthi + ((size_t)(b * 64 + col)) * 1024;
        const unsigned short* blp = htlo + ((size_t)(b * 64 + col)) * 1024;
        f32x4 acc = {0.f, 0.f, 0.f, 0.f};
        #pragma unroll 8
        for (int kst = 0; kst < 32; ++kst) {
            unsigned cc = ((unsigned)(kst * 4 + kg)) ^ ((unsigned)(arow & 7));
            bf16x8 pa = *(const bf16x8*)((char*)Pl + arow * 2048 + cc * 16);
            bf16x8 vh = *(const bf16x8*)&bhp[kst * 32 + kg * 8];
            bf16x8 vl = *(const bf16x8*)&blp[kst * 32 + kg * 8];
            acc = __builtin_amdgcn_mfma_f32_16x16x32_bf16(pa, vh, acc, 0, 0, 0);
            acc = __builtin_amdgcn_mfma_f32_16x16x32_bf16(pa, vl, acc, 0, 0, 0);
        }
        size_t base = (size_t)(b * NN + i0);
        #pragma unroll
        for (int r = 0; r < 4; ++r) {
            int orow = kg * 4 + r;
            float v = acc[r] * rdeninv[orow];
            h_prime[(base + orow) * 128 + col] = v;
        }
    }
}

// ================= Kernel 3: ma attention + h_prime_ma ======================
// block = 256 threads, handles 8 n's (2 at a time); h_ma staged in LDS.
__global__ __launch_bounds__(256) void k3_maatt(
    const float* __restrict__ z, const unsigned long long* __restrict__ opmb,
    const float* __restrict__ h, const float* __restrict__ h_ma,
    const float* __restrict__ ham1, const float* __restrict__ hmaam2,
    const int* __restrict__ rmask, const float* __restrict__ wam3,
    const float* __restrict__ w_edge, float* __restrict__ h_prime)
{
    __shared__ float hma_s[128 * 64];      // 32 KB
    __shared__ float u_s[2][128];
    __shared__ float redmx[4], redsm[4];
    __shared__ float part[2][8][16];
    __shared__ float zsum_s[2][16];
    __shared__ float hmp[2][2][64];
    __shared__ float wam3s[16];
    __shared__ float rdens[2];

    int bid = blockIdx.x;
    int b = bid >> 7;
    int n0 = (bid & 127) * 8;
    int t = threadIdx.x;
    int wvid = t >> 6;

    {
        const float4* src = (const float4*)(h_ma + (size_t)b * MM * 64);
        float4* dst = (float4*)hma_s;
        #pragma unroll
        for (int it = 0; it < 8; ++it) dst[t + 256 * it] = src[t + 256 * it];
    }
    if (t < 16) wam3s[t] = wam3[t];
    __syncthreads();

    for (int pp = 0; pp < 4; ++pp) {
        int nsel = t >> 7;
        int m = t & 127;
        int n = n0 + pp * 2 + nsel;
        int bn = b * NN + n;

        // ---- e / u ----
        size_t zbase = ((size_t)bn * MM + m) * 16;
        float4 z0 = *(const float4*)(z + zbase);
        float4 z1 = *(const float4*)(z + zbase + 4);
        float4 z2 = *(const float4*)(z + zbase + 8);
        float4 z3 = *(const float4*)(z + zbase + 12);
        float e = ham1[bn] + hmaam2[b * MM + m];
        e += z0.x*wam3s[0] + z0.y*wam3s[1] + z0.z*wam3s[2] + z0.w*wam3s[3];
        e += z1.x*wam3s[4] + z1.y*wam3s[5] + z1.z*wam3s[6] + z1.w*wam3s[7];
        e += z2.x*wam3s[8] + z2.y*wam3s[9] + z2.z*wam3s[10] + z2.w*wam3s[11];
        e += z3.x*wam3s[12] + z3.y*wam3s[13] + z3.z*wam3s[14] + z3.w*wam3s[15];
        e = e > 0.f ? e : 0.01f * e;
        unsigned long long bits = opmb[(size_t)bn * 2 + (m >> 6)];
        int valid = rmask[bn] | (int)((bits >> (m & 63)) & 1ULL);
        e = valid ? e : -INFINITY;

        float mx = e;
        #pragma unroll
        for (int msk = 32; msk; msk >>= 1) mx = fmaxf(mx, __shfl_xor(mx, msk));
        if ((t & 63) == 0) redmx[wvid] = mx;
        __syncthreads();
        mx = fmaxf(redmx[nsel * 2], redmx[nsel * 2 + 1]);
        float uu = __expf(e - mx);
        u_s[nsel][m] = uu;
        float sv = uu;
        #pragma unroll
        for (int msk = 32; msk; msk >>= 1) sv += __shfl_xor(sv, msk);
        if ((t & 63) == 0) redsm[wvid] = sv;
        __syncthreads();
        float den = redsm[nsel * 2] + redsm[nsel * 2 + 1];
        if (m == 0) rdens[nsel] = 1.f / den;

        // ---- zsum partials: thread = (nsel2, g, i) ----
        {
            int i = t & 15;
            int g = (t >> 4) & 7;
            int ns2 = t >> 7;
            int bn2 = b * NN + n0 + pp * 2 + ns2;
            const float* zr = z + (size_t)bn2 * MM * 16;
            float facc = 0.f;
            #pragma unroll
            for (int k = 0; k < 16; ++k) {
                int mm = g * 16 + k;
                facc += u_s[ns2][mm] * zr[(size_t)mm * 16 + i];
            }
            part[ns2][g][i] = facc;
        }
        // ---- h_ma matvec partials: thread = (nsel3, q, o) ----
        {
            int o = t & 63;
            int q = (t >> 6) & 1;
            int ns3 = t >> 7;
            float acc = 0.f;
            #pragma unroll 8
            for (int k = 0; k < 64; ++k) {
                int mm = q * 64 + k;
                acc += u_s[ns3][mm] * hma_s[mm * 64 + o];
            }
            hmp[ns3][q][o] = acc;
        }
        __syncthreads();
        if (t < 32) {
            int ns = t >> 4, i = t & 15;
            float zs = 0.f;
            #pragma unroll
            for (int g = 0; g < 8; ++g) zs += part[ns][g][i];
            zsum_s[ns][i] = zs;
        }
        __syncthreads();
        if (t < 128) {
            int ns = t >> 6, oo = t & 63;
            int bnf = b * NN + n0 + pp * 2 + ns;
            float he = 0.f;
            #pragma unroll
            for (int i = 0; i < 16; ++i) he += zsum_s[ns][i] * w_edge[i * 64 + oo];
            float val = (hmp[ns][0][oo] + hmp[ns][1][oo] + he) * rdens[ns]
                      + h[(size_t)bnf * 64 + oo];
            h_prime[(size_t)bnf * 128 + 64 + oo] = val;
        }
        __syncthreads();
    }
}

// ================= Kernel 4: MLP via MFMA (bf16 hi/lo split) ================
__global__ __launch_bounds__(256) void k4_mlp(
    const float* __restrict__ hp, const int* __restrict__ rmask,
    const unsigned short* __restrict__ wt1hi, const unsigned short* __restrict__ wt1lo,
    const unsigned short* __restrict__ wt2hi, const unsigned short* __restrict__ wt2lo,
    const unsigned short* __restrict__ wtohi, const unsigned short* __restrict__ wtolo,
    const float* __restrict__ b1, const float* __restrict__ b2,
    const float* __restrict__ bo, float* __restrict__ out)
{
    __shared__ __align__(16) unsigned short Ahi0[16 * 136];
    __shared__ __align__(16) unsigned short Alo0[16 * 136];
    __shared__ __align__(16) unsigned short Ahi1[16 * 136];
    __shared__ __align__(16) unsigned short Alo1[16 * 136];
    __shared__ int rml[16];
    int t = threadIdx.x;
    int lane = t & 63;
    int wv = t >> 6;
    int row0 = blockIdx.x * 16;

    // ---- stage input rows, split to hi/lo planes ----
    {
        int r = t >> 4;                 // 0..15
        int cg = (t & 15) * 8;          // 8-elem chunk
        const float* src = hp + (size_t)(row0 + r) * 128 + cg;
        float4 v0 = *(const float4*)src;
        float4 v1 = *(const float4*)(src + 4);
        float xs[8] = {v0.x, v0.y, v0.z, v0.w, v1.x, v1.y, v1.z, v1.w};
        u16x8 hv, lv;
        #pragma unroll
        for (int j = 0; j < 8; ++j) {
            unsigned short hs, ls;
            splitbf(xs[j], hs, ls);
            hv[j] = hs; lv[j] = ls;
        }
        *(u16x8*)&Ahi0[r * 136 + cg] = hv;
        *(u16x8*)&Alo0[r * 136 + cg] = lv;
        if (t < 16) rml[t] = rmask[row0 + t];
    }
    __syncthreads();

    int arow = lane & 15;
    int kg = lane >> 4;                 // 0..3
    int aoff = arow * 136 + kg * 8;

    // ---- layer 1: A0 -> A1 ----
    {
        bf16x8 ah[4], al[4];
        #pragma unroll
        for (int ks = 0; ks < 4; ++ks) {
            ah[ks] = *(const bf16x8*)&Ahi0[aoff + ks * 32];
            al[ks] = *(const bf16x8*)&Alo0[aoff + ks * 32];
        }
        #pragma unroll
        for (int q = 0; q < 2; ++q) {
            int ct = wv + q * 4;
            int col = ct * 16 + arow;
            const unsigned short* wh = wt1hi + (size_t)col * 128 + kg * 8;
            const unsigned short* wl = wt1lo + (size_t)col * 128 + kg * 8;
            f32x4 acc = {0.f, 0.f, 0.f, 0.f};
            #pragma unroll
            for (int ks = 0; ks < 4; ++ks) {
                bf16x8 bh = *(const bf16x8*)&wh[ks * 32];
                bf16x8 bl = *(const bf16x8*)&wl[ks * 32];
                acc = __builtin_amdgcn_mfma_f32_16x16x32_bf16(ah[ks], bh, acc, 0, 0, 0);
                acc = __builtin_amdgcn_mfma_f32_16x16x32_bf16(al[ks], bh, acc, 0, 0, 0);
                acc = __builtin_amdgcn_mfma_f32_16x16x32_bf16(ah[ks], bl, acc, 0, 0, 0);
            }
            float bb = b1[col];
            #pragma unroll
            for (int r = 0; r < 4; ++r) {
                int row = kg * 4 + r;
                float v = acc[r] + bb;
                v = v > 0.f ? v : __expf(v) - 1.f;
                unsigned short hs, ls;
                splitbf(v, hs, ls);
                Ahi1[row * 136 + col] = hs;
                Alo1[row * 136 + col] = ls;
            }
        }
    }
    __syncthreads();

    // ---- layer 2: A1 -> A0 ----
    {
        bf16x8 ah[4], al[4];
        #pragma unroll
        for (int ks = 0; ks < 4; ++ks) {
            ah[ks] = *(const bf16x8*)&Ahi1[aoff + ks * 32];
            al[ks] = *(const bf16x8*)&Alo1[aoff + ks * 32];
        }
        #pragma unroll
        for (int q = 0; q < 2; ++q) {
            int ct = wv + q * 4;
            int col = ct * 16 + arow;
            const unsigned short* wh = wt2hi + (size_t)col * 128 + kg * 8;
            const unsigned short* wl = wt2lo + (size_t)col * 128 + kg * 8;
            f32x4 acc = {0.f, 0.f, 0.f, 0.f};
            #pragma unroll
            for (int ks = 0; ks < 4; ++ks) {
                bf16x8 bh = *(const bf16x8*)&wh[ks * 32];
                bf16x8 bl = *(const bf16x8*)&wl[ks * 32];
                acc = __builtin_amdgcn_mfma_f32_16x16x32_bf16(ah[ks], bh, acc, 0, 0, 0);
                acc = __builtin_amdgcn_mfma_f32_16x16x32_bf16(al[ks], bh, acc, 0, 0, 0);
                acc = __builtin_amdgcn_mfma_f32_16x16x32_bf16(ah[ks], bl, acc, 0, 0, 0);
            }
            float bb = b2[col];
            #pragma unroll
            for (int r = 0; r < 4; ++r) {
                int row = kg * 4 + r;
                float v = acc[r] + bb;
                v = v > 0.f ? v : __expf(v) - 1.f;
                unsigned short hs, ls;
                splitbf(v, hs, ls);
                Ahi0[row * 136 + col] = hs;
                Alo0[row * 136 + col] = ls;
            }
        }
    }
    __syncthreads();

    // ---- layer 3 (output): A0 @ WO, + bo, rmask zero, store ----
    {
        bf16x8 ah[4], al[4];
        #pragma unroll
        for (int ks = 0; ks < 4; ++ks) {
            ah[ks] = *(const bf16x8*)&Ahi0[aoff + ks * 32];
            al[ks] = *(const bf16x8*)&Alo0[aoff + ks * 32];
        }
        int ct = wv;                    // 4 coltiles of 16 -> 64 cols
        int col = ct * 16 + arow;
        const unsigned short* wh = wtohi + (size_t)col * 128 + kg * 8;
        const unsigned short* wl = wtolo + (size_t)col * 128 + kg * 8;
        f32x4 acc = {0.f, 0.f, 0.f, 0.f};
        #pragma unroll
        for (int ks = 0; ks < 4; ++ks) {
            bf16x8 bh = *(const bf16x8*)&wh[ks * 32];
            bf16x8 bl = *(const bf16x8*)&wl[ks * 32];
            acc = __builtin_amdgcn_mfma_f32_16x16x32_bf16(ah[ks], bh, acc, 0, 0, 0);
            acc = __builtin_amdgcn_mfma_f32_16x16x32_bf16(al[ks], bh, acc, 0, 0, 0);
            acc = __builtin_amdgcn_mfma_f32_16x16x32_bf16(ah[ks], bl, acc, 0, 0, 0);
        }
        float bb = bo[col];
        #pragma unroll
        for (int r = 0; r < 4; ++r) {
            int row = kg * 4 + r;
            float v = acc[r] + bb;
            out[(size_t)(row0 + row) * 64 + col] = rml[row] ? 0.f : v;
        }
    }
}

// ============================ launch ========================================
extern "C" void kernel_launch(void* const* d_in, const int* in_sizes, int n_in,
                              void* d_out, int out_size, void* d_ws, size_t ws_size,
                              hipStream_t stream) {
    const float* x      = (const float*)d_in[0];
    const float* y      = (const float*)d_in[1];
    const float* z      = (const float*)d_in[2];
    const int*   op_adj = (const int*)d_in[3];
    const int*   ma_adj = (const int*)d_in[4];
    const int*   opma   = (const int*)d_in[5];
    const float* w_op   = (const float*)d_in[6];
    const float* w_ma   = (const float*)d_in[7];
    const float* w_edge = (const float*)d_in[8];
    const float* att_op = (const float*)d_in[9];
    const float* att_ma = (const float*)d_in[10];
    const float* w1     = (const float*)d_in[11];
    const float* b1     = (const float*)d_in[12];
    const float* w2     = (const float*)d_in[13];
    const float* b2     = (const float*)d_in[14];
    const float* wo     = (const float*)d_in[15];
    const float* bo     = (const float*)d_in[16];
    float* out = (float*)d_out;

    float* ws = (float*)d_ws;
    float* h       = ws + OFF_H;
    float* h_ma    = ws + OFF_HMA;
    float* ha1     = ws + OFF_HA1;
    float* ha2     = ws + OFF_HA2;
    float* ham1    = ws + OFF_HAM1;
    float* hmaam2  = ws + OFF_HMAAM2;
    int*   rmask   = (int*)(ws + OFF_RMASK);
    float* wam3    = ws + OFF_WAM3;
    float* h_prime = ws + OFF_HPRIME;
    unsigned* upack = (unsigned*)(ws + OFF_UPACK);
    unsigned long long* opmb = (unsigned long long*)(ws + OFF_OPMB);
    unsigned short* wt1hi = (unsigned short*)(ws + OFF_WT1HI);
    unsigned short* wt1lo = (unsigned short*)(ws + OFF_WT1LO);
    unsigned short* wt2hi = (unsigned short*)(ws + OFF_WT2HI);
    unsigned short* wt2lo = (unsigned short*)(ws + OFF_WT2LO);
    unsigned short* wtohi = (unsigned short*)(ws + OFF_WTOHI);
    unsigned short* wtolo = (unsigned short*)(ws + OFF_WTOLO);
    unsigned short* hthi  = (unsigned short*)(ws + OFF_HTHI);
    unsigned short* htlo  = (unsigned short*)(ws + OFF_HTLO);

    k1_prep<<<2048 + 256 + 1 + 1088 + 40, 256, 0, stream>>>(
        x, y, opma, op_adj, ma_adj, w_op, w_ma, w_edge, att_op, att_ma,
        w1, w2, wo,
        h, h_ma, ha1, ha2, ham1, hmaam2, rmask, wam3, upack, opmb,
        wt1hi, wt1lo, wt2hi, wt2lo, wtohi, wtolo, hthi, htlo);

    k2_opatt<<<512, 256, 0, stream>>>(
        upack, hthi, htlo, ha1, ha2, rmask, h_prime);

    k3_maatt<<<1024, 256, 0, stream>>>(
        z, opmb, h, h_ma, ham1, hmaam2, rmask, wam3, w_edge, h_prime);

    k4_mlp<<<512, 256, 0, stream>>>(
        h_prime, rmask, wt1hi, wt1lo, wt2hi, wt2lo, wtohi, wtolo,
        b1, b2, bo, out);
}